// Round 2
// baseline (10140.763 us; speedup 1.0000x reference)
//
#include <hip/hip_runtime.h>
#include <math.h>

// ---------------- device helpers ----------------
__device__ __forceinline__ float gelu_tanh(float x){
  float x3 = x*x*x;
  return 0.5f*x*(1.0f + tanhf(0.79788456080286535588f*(x + 0.044715f*x3)));
}
__device__ __forceinline__ float wave_sum(float v){
  #pragma unroll
  for (int o=32;o>0;o>>=1) v += __shfl_down(v,o);
  return v;
}
__device__ __forceinline__ float wave_max(float v){
  #pragma unroll
  for (int o=32;o>0;o>>=1) v = fmaxf(v, __shfl_down(v,o));
  return v;
}

// ---------------- embed: per-file linear + transpose + PE(F,S) ----------------
// X[b,f,s] = dot(x[b,s,f*16:+16], lin_w[f,:]) + lin_b[f] + pe(pos=f, dim=s, d=256)
__global__ __launch_bounds__(256) void k_embed(const float* __restrict__ x,
    const float* __restrict__ lw, const float* __restrict__ lb,
    float* __restrict__ X)
{
  int idx = blockIdx.x*256 + threadIdx.x;      // (b*128+f)*256+s
  int s = idx & 255;
  int f = (idx >> 8) & 127;
  int b = idx >> 15;
  const float* xr = x + ((long)(b*256 + s))*2048 + f*16;
  const float* wr = lw + f*16;
  float acc = lb[f];
  #pragma unroll
  for (int c=0;c<16;c++) acc = fmaf(xr[c], wr[c], acc);
  int i = s >> 1;
  float dv = expf((float)(2*i) * (-9.210340371976184f/256.0f));
  float ang = (float)f * dv;
  acc += (s & 1) ? cosf(ang) : sinf(ang);
  X[idx] = acc;
}

// ---------------- transpose [B,128,256]->[B,256,128] + PE(S,F) ----------------
__global__ __launch_bounds__(256) void k_transpose_pe(const float* __restrict__ X,
    float* __restrict__ Y)
{
  int idx = blockIdx.x*256 + threadIdx.x;      // (b*256+s)*128+f
  int f = idx & 127;
  int s = (idx >> 7) & 255;
  int b = idx >> 15;
  int i = f >> 1;
  float dv = expf((float)(2*i) * (-9.210340371976184f/128.0f));
  float ang = (float)s * dv;
  float pe = (f & 1) ? cosf(ang) : sinf(ang);
  Y[idx] = X[((long)(b*128 + f))*256 + s] + pe;
}

// ---------------- layernorm (wave per row) ----------------
__global__ __launch_bounds__(256) void k_ln(const float* __restrict__ X,
    const float* __restrict__ w, const float* __restrict__ b,
    float* __restrict__ Y, int R, int D)
{
  int row = blockIdx.x*4 + (threadIdx.x >> 6);
  int lane = threadIdx.x & 63;
  if (row >= R) return;
  const float* xr = X + (long)row*D;
  float sum=0.f, sq=0.f;
  for (int i=lane;i<D;i+=64){ float v=xr[i]; sum+=v; sq+=v*v; }
  sum = wave_sum(sum); sq = wave_sum(sq);
  sum = __shfl(sum,0); sq = __shfl(sq,0);
  float mu = sum/(float)D;
  float var = sq/(float)D - mu*mu;
  float inv = rsqrtf(var + 1e-5f);
  float* yr = Y + (long)row*D;
  for (int i=lane;i<D;i+=64) yr[i] = (xr[i]-mu)*inv*w[i] + b[i];
}

// ---------------- generic GEMM: C = A[M,K] @ W[K,N] (+bias)(+gelu)(+res) ----------------
// requires M%64==0, N%64==0, K%16==0
template<int ACT>
__global__ __launch_bounds__(256) void k_gemm(
    const float* __restrict__ A, const float* __restrict__ W,
    const float* __restrict__ bias, const float* __restrict__ res,
    float* __restrict__ C, int M, int N, int K)
{
  __shared__ float As[16][65];
  __shared__ float Ws[16][65];
  const int tid = threadIdx.x;
  const int r0 = blockIdx.y*64, c0 = blockIdx.x*64;
  const int ty = tid>>4, tx = tid&15;
  const int ar = tid>>2, akq = (tid&3)*4;
  const int wc = tid&63, wkb = (tid>>6)*4;
  float acc[4][4] = {};
  for (int k0=0;k0<K;k0+=16){
    float4 av = *reinterpret_cast<const float4*>(A + (long)(r0+ar)*K + k0 + akq);
    As[akq+0][ar]=av.x; As[akq+1][ar]=av.y; As[akq+2][ar]=av.z; As[akq+3][ar]=av.w;
    #pragma unroll
    for (int kk=0;kk<4;kk++)
      Ws[wkb+kk][wc] = W[(long)(k0+wkb+kk)*N + c0+wc];
    __syncthreads();
    #pragma unroll
    for (int k=0;k<16;k++){
      float a[4], bb[4];
      #pragma unroll
      for (int i=0;i<4;i++) a[i] = As[k][ty*4+i];
      #pragma unroll
      for (int j=0;j<4;j++) bb[j] = Ws[k][tx*4+j];
      #pragma unroll
      for (int i=0;i<4;i++)
        #pragma unroll
        for (int j=0;j<4;j++) acc[i][j] = fmaf(a[i], bb[j], acc[i][j]);
    }
    __syncthreads();
  }
  #pragma unroll
  for (int i=0;i<4;i++){
    const int r = r0 + ty*4 + i;
    #pragma unroll
    for (int j=0;j<4;j++){
      const int c = c0 + tx*4 + j;
      float v = acc[i][j];
      if (bias) v += bias[c];
      if (ACT==1) v = gelu_tanh(v);
      if (res) v += res[(long)r*N + c];
      C[(long)r*N + c] = v;
    }
  }
}

// ---------------- batched strided GEMM ----------------
// per bh in [0,B*H): C(r,c) = alpha * sum_k A(r,k)*B(k,c)   [* rowscale[bh*R+r]]
// A(r,k) at A + b*Ab + h*Ah + r*Ar + k*Ak ; B(k,c) at B + b*Bb + h*Bh + k*Bk + c*Bc
// C(r,c) at C + b*Cb + h*Ch + r*Cr + c    (c contiguous)
__global__ __launch_bounds__(256) void k_bgemm(
    const float* __restrict__ A, const float* __restrict__ Bm,
    float* __restrict__ Cm, const float* __restrict__ rowscale, float alpha,
    int H, int R, int NC, int K,
    long Ab, long Ah, long Ar, long Ak,
    long Bb, long Bh, long Bk, long Bc,
    long Cb, long Ch, long Cr)
{
  __shared__ float As[16][65];
  __shared__ float Bs[16][65];
  const int tid = threadIdx.x;
  const int bh = blockIdx.z;
  const int b = bh / H, h = bh - b*H;
  const float* Ap = A + (long)b*Ab + (long)h*Ah;
  const float* Bp = Bm + (long)b*Bb + (long)h*Bh;
  float* Cp = Cm + (long)b*Cb + (long)h*Ch;
  const int c0 = blockIdx.x*64, r0 = blockIdx.y*64;
  const int ty = tid>>4, tx = tid&15;
  float acc[4][4] = {};
  for (int k0=0;k0<K;k0+=16){
    if (Ak == 1){
      int k = tid&15, rb = (tid>>4)*4;
      #pragma unroll
      for (int rr=0;rr<4;rr++){
        int r = rb+rr; float v = 0.f;
        if (r0+r < R && k0+k < K) v = Ap[(long)(r0+r)*Ar + (k0+k)];
        As[k][r] = v*alpha;
      }
    } else {
      int r = tid&63, kb = (tid>>6)*4;
      #pragma unroll
      for (int kk=0;kk<4;kk++){
        int k = kb+kk; float v = 0.f;
        if (r0+r < R && k0+k < K) v = Ap[(long)(r0+r)*Ar + (long)(k0+k)*Ak];
        As[k][r] = v*alpha;
      }
    }
    if (Bc == 1){
      int c = tid&63, kb = (tid>>6)*4;
      #pragma unroll
      for (int kk=0;kk<4;kk++){
        int k = kb+kk; float v = 0.f;
        if (c0+c < NC && k0+k < K) v = Bp[(long)(k0+k)*Bk + (c0+c)];
        Bs[k][c] = v;
      }
    } else {
      int k = tid&15, cb = (tid>>4)*4;
      #pragma unroll
      for (int cc=0;cc<4;cc++){
        int c = cb+cc; float v = 0.f;
        if (c0+c < NC && k0+k < K) v = Bp[(long)(k0+k)*Bk + (long)c*Bc];
        Bs[k][c] = v;
      }
    }
    __syncthreads();
    #pragma unroll
    for (int k=0;k<16;k++){
      float a[4], bb[4];
      #pragma unroll
      for (int i=0;i<4;i++) a[i] = As[k][ty*4+i];
      #pragma unroll
      for (int j=0;j<4;j++) bb[j] = Bs[k][tx*4+j];
      #pragma unroll
      for (int i=0;i<4;i++)
        #pragma unroll
        for (int j=0;j<4;j++) acc[i][j] = fmaf(a[i], bb[j], acc[i][j]);
    }
    __syncthreads();
  }
  #pragma unroll
  for (int i=0;i<4;i++){
    const int r = r0 + ty*4 + i;
    if (r >= R) continue;
    float rs = rowscale ? rowscale[(long)bh*R + r] : 1.0f;
    #pragma unroll
    for (int j=0;j<4;j++){
      const int c = c0 + tx*4 + j;
      if (c >= NC) continue;
      Cp[(long)r*Cr + c] = acc[i][j]*rs;
    }
  }
}

// ---------------- diag: 0.5*dn^2*||row||^2 over [B,n,I] rows (b,h,n) ----------------
__global__ __launch_bounds__(256) void k_diag(const float* __restrict__ src,
    float* __restrict__ out, int rows, int n, int I, int dh, int H, float dn)
{
  int row = blockIdx.x*4 + (threadIdx.x >> 6);
  int lane = threadIdx.x & 63;
  if (row >= rows) return;
  int ni = row % n; int bhh = row / n; int h = bhh % H; int b = bhh / H;
  const float* p = src + ((long)(b*n + ni))*I + h*dh;
  float s = 0.f;
  for (int i=lane;i<dh;i+=64){ float v=p[i]; s += v*v; }
  s = wave_sum(s);
  if (lane==0) out[row] = 0.5f*dn*dn*s;
}

// ---------------- global max (2-pass) ----------------
__global__ __launch_bounds__(256) void k_gmax1(const float* __restrict__ PP,
    float* __restrict__ red, long count)
{
  float mx = -INFINITY;
  for (long i = (long)blockIdx.x*256 + threadIdx.x; i < count; i += (long)gridDim.x*256)
    mx = fmaxf(mx, PP[i]);
  __shared__ float sm[4];
  int lane = threadIdx.x & 63, wid = threadIdx.x >> 6;
  mx = wave_max(mx);
  if (lane==0) sm[wid]=mx;
  __syncthreads();
  if (threadIdx.x==0){
    float v = fmaxf(fmaxf(sm[0],sm[1]), fmaxf(sm[2],sm[3]));
    red[blockIdx.x] = v;
  }
}
__global__ __launch_bounds__(256) void k_gmax2(const float* __restrict__ red,
    float* __restrict__ out, int cnt)
{
  float mx = -INFINITY;
  for (int i=threadIdx.x;i<cnt;i+=256) mx = fmaxf(mx, red[i]);
  __shared__ float sm[4];
  int lane = threadIdx.x & 63, wid = threadIdx.x >> 6;
  mx = wave_max(mx);
  if (lane==0) sm[wid]=mx;
  __syncthreads();
  if (threadIdx.x==0) out[0] = fmaxf(fmaxf(sm[0],sm[1]), fmaxf(sm[2],sm[3]));
}

// ---------------- rowmax over PP rows ----------------
__global__ __launch_bounds__(256) void k_rowmax(const float* __restrict__ PP,
    float* __restrict__ out, int rows, int M)
{
  int row = blockIdx.x*4 + (threadIdx.x >> 6);
  int lane = threadIdx.x & 63;
  if (row >= rows) return;
  const float* p = PP + (long)row*M;
  float mx = -INFINITY;
  for (int i=lane;i<M;i+=64) mx = fmaxf(mx, p[i]);
  mx = wave_max(mx);
  if (lane==0) out[row] = mx;
}

// ---------------- elementwise: pp = ratio*(exp(pp - diag[row] - stab) + eps) ----------------
template<bool PERROW>
__global__ __launch_bounds__(256) void k_exp(float* __restrict__ PP,
    const float* __restrict__ diag, const float* __restrict__ stab,
    long count, int M, float ratio, float eps)
{
  long idx = (long)blockIdx.x*256 + threadIdx.x;
  if (idx >= count) return;
  long row = idx / M;
  float st = PERROW ? stab[row] : stab[0];
  PP[idx] = ratio*(expf(PP[idx] - diag[row] - st) + eps);
}

// ---------------- column sum over n: kpsum[bh,m] = sum_n kp[bh,n,m] ----------------
__global__ __launch_bounds__(256) void k_colsum(const float* __restrict__ PP,
    float* __restrict__ out, int BH, int n, int M)
{
  int idx = blockIdx.x*256 + threadIdx.x;
  if (idx >= BH*M) return;
  int bh = idx / M, m = idx - bh*M;
  const float* p = PP + (long)bh*n*M + m;
  float s = 0.f;
  for (int i=0;i<n;i++) s += p[(long)i*M];
  out[idx] = s;
}

// ---------------- dinv[row] = 1 / dot(qp[row,:], kpsum[bh,:]) ----------------
__global__ __launch_bounds__(256) void k_dinv(const float* __restrict__ QP,
    const float* __restrict__ ksum, float* __restrict__ dinv, int rows, int n, int M)
{
  int row = blockIdx.x*4 + (threadIdx.x >> 6);
  int lane = threadIdx.x & 63;
  if (row >= rows) return;
  int bh = row / n;
  const float* q = QP + (long)row*M;
  const float* k = ksum + (long)bh*M;
  float s = 0.f;
  for (int i=lane;i<M;i+=64) s = fmaf(q[i], k[i], s);
  s = wave_sum(s);
  if (lane==0) dinv[row] = 1.0f/s;
}

// ---------------- final mean over s: out[b,f] = mean_s X[b,s,f] ----------------
__global__ __launch_bounds__(256) void k_mean(const float* __restrict__ X,
    float* __restrict__ out)
{
  int idx = blockIdx.x*256 + threadIdx.x;   // b*128+f
  int f = idx & 127, b = idx >> 7;
  const float* p = X + (long)b*256*128 + f;
  float s = 0.f;
  for (int i=0;i<256;i++) s += p[i*128];
  out[idx] = s*(1.0f/256.0f);
}

// ---------------- host-side stage driver ----------------
struct Stage {
  const float *ln1w,*ln1b,*wq,*wk,*wv,*wo,*wob,*ln2w,*ln2b,*f1w,*f1b,*f2w,*f2b,*proj;
  int n, D, H, dh, I, M;
};

static void run_stage(const Stage& P, float* X, float* LN, float* Q, float* K, float* V,
                      float* PP, float* CTX, float* ATTN, float* FFH,
                      float* KPSUM, float* DIAG, float* ROWMAX, float* DINV, float* RED,
                      hipStream_t stream)
{
  const int B = 64;
  const int rows = B*P.n;
  const int bh = B*P.H;
  const long ppcount = (long)bh*P.n*P.M;
  const float dn = powf((float)P.dh, -0.25f);
  const float ratio = 1.0f/sqrtf((float)P.M);

  for (int l=0;l<4;l++){
    const float* ln1w = P.ln1w + (long)l*P.D;
    const float* ln1b = P.ln1b + (long)l*P.D;
    const float* wq  = P.wq  + (long)l*P.D*P.I;
    const float* wk  = P.wk  + (long)l*P.D*P.I;
    const float* wv  = P.wv  + (long)l*P.D*P.I;
    const float* wo  = P.wo  + (long)l*P.I*P.D;
    const float* wob = P.wob + (long)l*P.D;
    const float* ln2w = P.ln2w + (long)l*P.D;
    const float* ln2b = P.ln2b + (long)l*P.D;
    const float* f1w = P.f1w + (long)l*P.D*4*P.D;
    const float* f1b = P.f1b + (long)l*4*P.D;
    const float* f2w = P.f2w + (long)l*4*P.D*P.D;
    const float* f2b = P.f2b + (long)l*P.D;
    const float* proj = P.proj + (long)l*P.M*P.dh;

    k_ln<<<dim3((rows+3)/4),dim3(256),0,stream>>>(X, ln1w, ln1b, LN, rows, P.D);
    dim3 gq(P.I/64, rows/64);
    k_gemm<0><<<gq,dim3(256),0,stream>>>(LN, wq, nullptr, nullptr, Q, rows, P.I, P.D);
    k_gemm<0><<<gq,dim3(256),0,stream>>>(LN, wk, nullptr, nullptr, K, rows, P.I, P.D);
    k_gemm<0><<<gq,dim3(256),0,stream>>>(LN, wv, nullptr, nullptr, V, rows, P.I, P.D);

    dim3 gdd((P.M+63)/64, (P.n+63)/64, bh);
    // dd_k -> PP
    k_bgemm<<<gdd,dim3(256),0,stream>>>(K, proj, PP, nullptr, dn,
        P.H, P.n, P.M, P.dh,
        (long)P.n*P.I, (long)P.dh, (long)P.I, 1L,
        0L, 0L, 1L, (long)P.dh,
        (long)P.H*P.n*P.M, (long)P.n*P.M, (long)P.M);
    k_diag<<<dim3((bh*P.n+3)/4),dim3(256),0,stream>>>(K, DIAG, bh*P.n, P.n, P.I, P.dh, P.H, dn);
    k_gmax1<<<dim3(2048),dim3(256),0,stream>>>(PP, RED, ppcount);
    k_gmax2<<<dim3(1),dim3(256),0,stream>>>(RED, RED+2048, 2048);
    k_exp<false><<<dim3((int)((ppcount+255)/256)),dim3(256),0,stream>>>(PP, DIAG, RED+2048, ppcount, P.M, ratio, 1e-4f);
    // ctx = kp^T @ v
    dim3 gctx((P.dh+63)/64, (P.M+63)/64, bh);
    k_bgemm<<<gctx,dim3(256),0,stream>>>(PP, V, CTX, nullptr, 1.0f,
        P.H, P.M, P.dh, P.n,
        (long)P.H*P.n*P.M, (long)P.n*P.M, 1L, (long)P.M,
        (long)P.n*P.I, (long)P.dh, (long)P.I, 1L,
        (long)P.H*P.M*P.dh, (long)P.M*P.dh, (long)P.dh);
    k_colsum<<<dim3((bh*P.M+255)/256),dim3(256),0,stream>>>(PP, KPSUM, bh, P.n, P.M);
    // dd_q -> PP (overwrite)
    k_bgemm<<<gdd,dim3(256),0,stream>>>(Q, proj, PP, nullptr, dn,
        P.H, P.n, P.M, P.dh,
        (long)P.n*P.I, (long)P.dh, (long)P.I, 1L,
        0L, 0L, 1L, (long)P.dh,
        (long)P.H*P.n*P.M, (long)P.n*P.M, (long)P.M);
    k_diag<<<dim3((bh*P.n+3)/4),dim3(256),0,stream>>>(Q, DIAG, bh*P.n, P.n, P.I, P.dh, P.H, dn);
    k_rowmax<<<dim3((bh*P.n+3)/4),dim3(256),0,stream>>>(PP, ROWMAX, bh*P.n, P.M);
    k_exp<true><<<dim3((int)((ppcount+255)/256)),dim3(256),0,stream>>>(PP, DIAG, ROWMAX, ppcount, P.M, ratio, 1e-4f);
    k_dinv<<<dim3((bh*P.n+3)/4),dim3(256),0,stream>>>(PP, KPSUM, DINV, bh*P.n, P.n, P.M);
    // out = (qp @ ctx) * dinv -> ATTN [B, n, I]
    dim3 gout((P.dh+63)/64, (P.n+63)/64, bh);
    k_bgemm<<<gout,dim3(256),0,stream>>>(PP, CTX, ATTN, DINV, 1.0f,
        P.H, P.n, P.dh, P.M,
        (long)P.H*P.n*P.M, (long)P.n*P.M, (long)P.M, 1L,
        (long)P.H*P.M*P.dh, (long)P.M*P.dh, (long)P.dh, 1L,
        (long)P.n*P.I, (long)P.dh, (long)P.I);
    // x = x + attn @ wo + wob
    dim3 gwo(P.D/64, rows/64);
    k_gemm<0><<<gwo,dim3(256),0,stream>>>(ATTN, wo, wob, X, X, rows, P.D, P.I);
    // ff block
    k_ln<<<dim3((rows+3)/4),dim3(256),0,stream>>>(X, ln2w, ln2b, LN, rows, P.D);
    dim3 gf1(4*P.D/64, rows/64);
    k_gemm<1><<<gf1,dim3(256),0,stream>>>(LN, f1w, f1b, nullptr, FFH, rows, 4*P.D, P.D);
    dim3 gf2(P.D/64, rows/64);
    k_gemm<0><<<gf2,dim3(256),0,stream>>>(FFH, f2w, f2b, X, X, rows, P.D, 4*P.D);
  }
}

// ---------------- entry ----------------
extern "C" void kernel_launch(void* const* d_in, const int* in_sizes, int n_in,
                              void* d_out, int out_size, void* d_ws, size_t ws_size,
                              hipStream_t stream)
{
  const float* x     = (const float*)d_in[0];
  const float* lin_w = (const float*)d_in[1];
  const float* lin_b = (const float*)d_in[2];

  Stage T;
  T.ln1w=(const float*)d_in[3];  T.ln1b=(const float*)d_in[4];
  T.wq=(const float*)d_in[5];    T.wk=(const float*)d_in[6];   T.wv=(const float*)d_in[7];
  T.wo=(const float*)d_in[8];    T.wob=(const float*)d_in[9];
  T.ln2w=(const float*)d_in[10]; T.ln2b=(const float*)d_in[11];
  T.f1w=(const float*)d_in[12];  T.f1b=(const float*)d_in[13];
  T.f2w=(const float*)d_in[14];  T.f2b=(const float*)d_in[15];
  T.proj=(const float*)d_in[16];
  T.n=128; T.D=256; T.H=5; T.dh=128; T.I=640; T.M=620;

  Stage Mstg;
  Mstg.ln1w=(const float*)d_in[17]; Mstg.ln1b=(const float*)d_in[18];
  Mstg.wq=(const float*)d_in[19];   Mstg.wk=(const float*)d_in[20]; Mstg.wv=(const float*)d_in[21];
  Mstg.wo=(const float*)d_in[22];   Mstg.wob=(const float*)d_in[23];
  Mstg.ln2w=(const float*)d_in[24]; Mstg.ln2b=(const float*)d_in[25];
  Mstg.f1w=(const float*)d_in[26];  Mstg.f1b=(const float*)d_in[27];
  Mstg.f2w=(const float*)d_in[28];  Mstg.f2b=(const float*)d_in[29];
  Mstg.proj=(const float*)d_in[30];
  Mstg.n=256; Mstg.D=128; Mstg.H=4; Mstg.dh=64; Mstg.I=256; Mstg.M=266;

  // workspace layout (floats)
  float* ws = (float*)d_ws;
  size_t off = 0;
  auto alloc = [&](size_t nel){ float* p = ws + off; off += nel; return p; };
  float* X     = alloc(2097152);   // [B,128,256] stage-1 activations
  float* X2    = alloc(2097152);   // [B,256,128] stage-2 activations
  float* LN    = alloc(2097152);
  float* Q     = alloc(5242880);
  float* K     = alloc(5242880);
  float* V     = alloc(5242880);
  float* PP    = alloc(25395200);  // dd / kp / qp
  float* CTX   = alloc(25395200);
  float* ATTN  = alloc(5242880);
  float* FFH   = alloc(8388608);
  float* KPSUM = alloc(198400);
  float* DIAG  = alloc(65536);
  float* ROWMAX= alloc(65536);
  float* DINV  = alloc(65536);
  float* RED   = alloc(2064);      // 2048 partials + scalar
  if (ws_size < off*sizeof(float)) return;  // insufficient scratch: fail loudly in validation

  // stage 0: per-file linear + transpose + PE(F,S)
  k_embed<<<dim3(8192),dim3(256),0,stream>>>(x, lin_w, lin_b, X);
  // ticker-major performer (seq=128, dim=256)
  run_stage(T, X, LN, Q, K, V, PP, CTX, ATTN, FFH, KPSUM, DIAG, ROWMAX, DINV, RED, stream);
  // transpose to time-major + PE(S,F)
  k_transpose_pe<<<dim3(8192),dim3(256),0,stream>>>(X, X2);
  // time-major performer (seq=256, dim=128)
  run_stage(Mstg, X2, LN, Q, K, V, PP, CTX, ATTN, FFH, KPSUM, DIAG, ROWMAX, DINV, RED, stream);
  // mean over time
  k_mean<<<dim3(32),dim3(256),0,stream>>>(X2, (float*)d_out);
}

// Round 3
// 4227.475 us; speedup vs baseline: 2.3988x; 2.3988x over previous
//
#include <hip/hip_runtime.h>
#include <math.h>

using bf16x8 = __attribute__((ext_vector_type(8))) short;
using f32x4  = __attribute__((ext_vector_type(4))) float;
using u16x8  = __attribute__((ext_vector_type(8))) unsigned short;
using u16x4  = __attribute__((ext_vector_type(4))) unsigned short;

__device__ __forceinline__ float b2f(unsigned short u){
  union{float f; unsigned int i;} x; x.i = ((unsigned int)u)<<16; return x.f;
}
__device__ __forceinline__ unsigned short f2b(float f){
  union{float f; unsigned int i;} x; x.f = f;
  unsigned int r = x.i + 0x7fffu + ((x.i>>16)&1u);
  return (unsigned short)(r>>16);
}
__device__ __forceinline__ float gelu_tanh(float x){
  float x3 = x*x*x;
  return 0.5f*x*(1.0f + tanhf(0.79788456080286535588f*(x + 0.044715f*x3)));
}
__device__ __forceinline__ float wave_sum(float v){
  #pragma unroll
  for (int o=32;o>0;o>>=1) v += __shfl_down(v,o);
  return v;
}
__device__ __forceinline__ float wave_max(float v){
  #pragma unroll
  for (int o=32;o>0;o>>=1) v = fmaxf(v, __shfl_down(v,o));
  return v;
}

// ---------------- embed: per-file linear + transpose + PE(F,S) ----------------
__global__ __launch_bounds__(256) void k_embed(const float* __restrict__ x,
    const float* __restrict__ lw, const float* __restrict__ lb,
    float* __restrict__ X)
{
  int idx = blockIdx.x*256 + threadIdx.x;      // (b*128+f)*256+s
  int s = idx & 255;
  int f = (idx >> 8) & 127;
  int b = idx >> 15;
  const float* xr = x + ((long)(b*256 + s))*2048 + f*16;
  const float* wr = lw + f*16;
  float acc = lb[f];
  #pragma unroll
  for (int c=0;c<16;c++) acc = fmaf(xr[c], wr[c], acc);
  int i = s >> 1;
  float dv = expf((float)(2*i) * (-9.210340371976184f/256.0f));
  float ang = (float)f * dv;
  acc += (s & 1) ? cosf(ang) : sinf(ang);
  X[idx] = acc;
}

// ---------------- transpose [B,128,256]->[B,256,128] + PE(S,F) ----------------
__global__ __launch_bounds__(256) void k_transpose_pe(const float* __restrict__ X,
    float* __restrict__ Y)
{
  int idx = blockIdx.x*256 + threadIdx.x;      // (b*256+s)*128+f
  int f = idx & 127;
  int s = (idx >> 7) & 255;
  int b = idx >> 15;
  int i = f >> 1;
  float dv = expf((float)(2*i) * (-9.210340371976184f/128.0f));
  float ang = (float)s * dv;
  float pe = (f & 1) ? cosf(ang) : sinf(ang);
  Y[idx] = X[((long)(b*128 + f))*256 + s] + pe;
}

// ---------------- layernorm: fp32 in -> bf16 out ----------------
__global__ __launch_bounds__(256) void k_ln(const float* __restrict__ X,
    const float* __restrict__ w, const float* __restrict__ b,
    unsigned short* __restrict__ Y, int R, int D)
{
  int row = blockIdx.x*4 + (threadIdx.x >> 6);
  int lane = threadIdx.x & 63;
  if (row >= R) return;
  const float* xr = X + (long)row*D;
  float sum=0.f, sq=0.f;
  for (int i=lane;i<D;i+=64){ float v=xr[i]; sum+=v; sq+=v*v; }
  sum = wave_sum(sum); sq = wave_sum(sq);
  sum = __shfl(sum,0); sq = __shfl(sq,0);
  float mu = sum/(float)D;
  float var = sq/(float)D - mu*mu;
  float inv = rsqrtf(var + 1e-5f);
  unsigned short* yr = Y + (long)row*D;
  for (int i=lane;i<D;i+=64) yr[i] = f2b((xr[i]-mu)*inv*w[i] + b[i]);
}

// ---------------- weight transpose-convert: W[L][K][N] f32 -> WT[L][N][K] bf16 ----------------
__global__ __launch_bounds__(256) void k_wt(const float* __restrict__ W,
    unsigned short* __restrict__ WT, int K, int N)
{
  __shared__ float t[32][33];
  int l = blockIdx.z;
  const float* Wp = W + (long)l*K*N;
  unsigned short* Tp = WT + (long)l*K*N;
  int tx = threadIdx.x & 31, ty = threadIdx.x >> 5;
  int kb = blockIdx.y*32, nb = blockIdx.x*32;
  #pragma unroll
  for (int i=0;i<4;i++) t[ty+i*8][tx] = Wp[(long)(kb+ty+i*8)*N + nb+tx];
  __syncthreads();
  #pragma unroll
  for (int i=0;i<4;i++) Tp[(long)(nb+ty+i*8)*K + kb+tx] = f2b(t[tx][ty+i*8]);
}

// ---------------- proj convert + pad: [L][M][dh] f32 -> [L][Mp][dh] bf16 (pad rows zero) ---------
__global__ __launch_bounds__(256) void k_projconv(const float* __restrict__ proj,
    unsigned short* __restrict__ pb, int M, int Mp, int dh, long total)
{
  long idx = (long)blockIdx.x*256 + threadIdx.x;
  if (idx >= total) return;
  int c = (int)(idx % dh);
  long t = idx / dh;
  int m = (int)(t % Mp);
  int l = (int)(t / Mp);
  pb[idx] = (m < M) ? f2b(proj[((long)l*M + m)*dh + c]) : (unsigned short)0;
}

// ---------------- generic MFMA GEMM ----------------
// C[R,NC] = alpha * A·B (+bias)(+gelu)(+rowscale)(+res), K multiple of 32.
// A_CM: A(r,k)=Ap[k*lda+r] else Ap[r*lda+k].  B_CM: B(k,c)=Bp[c*ldb+k] else Bp[k*ldb+c].
// batch (grid.z): b=bz/H, h=bz%H applied via Ab/Ah etc.
template<bool A_CM, bool B_CM, int EPI, bool OUT_BF16>   // EPI: 0 none, 2 bias+gelu, 3 bias+res
__global__ __launch_bounds__(256) void k_mgemm(
    const unsigned short* __restrict__ A, const unsigned short* __restrict__ B,
    void* __restrict__ C, const float* __restrict__ bias,
    const float* __restrict__ res, const float* __restrict__ rowscale,
    float alpha, int H, int R, int NC, int K,
    long Ab, long Ah, long lda,
    long Bb, long Bh, long ldb,
    long Cb, long Ch, long ldc, int rsn)
{
  __shared__ unsigned short Asm[128][40];
  __shared__ unsigned short Bsm[128][40];
  const int tid = threadIdx.x;
  const int bz = blockIdx.z;
  const int b = bz / H, h = bz - b*H;
  const unsigned short* Ap = A + (long)b*Ab + (long)h*Ah;
  const unsigned short* Bp = B + (long)b*Bb + (long)h*Bh;
  const int r0 = blockIdx.y*128, c0 = blockIdx.x*128;
  const int wid = tid>>6, lane = tid&63;
  const int wr = wid>>1, wc = wid&1;
  const int lr = lane&15, lg = lane>>4;
  f32x4 acc[4][4] = {};

  for (int k0=0; k0<K; k0+=32){
    // ---- stage A tile -> Asm[r][k]
    if (!A_CM){
      #pragma unroll
      for (int it=0; it<2; ++it){
        int idx = tid + it*256;
        int r = idx>>2, kq = (idx&3)*8;
        u16x8 v = *reinterpret_cast<const u16x8*>(Ap + (long)(r0+r)*lda + (k0+kq));
        *reinterpret_cast<u16x8*>(&Asm[r][kq]) = v;
      }
    } else {
      #pragma unroll
      for (int it=0; it<2; ++it){
        int idx = tid + it*256;
        int k = idx>>4, rq = (idx&15)*8;
        u16x8 v = {};
        if (r0+rq < R) v = *reinterpret_cast<const u16x8*>(Ap + (long)(k0+k)*lda + (r0+rq));
        #pragma unroll
        for (int i=0;i<8;i++) Asm[rq+i][k] = v[i];
      }
    }
    // ---- stage B tile -> Bsm[c][k]
    if (B_CM){
      #pragma unroll
      for (int it=0; it<2; ++it){
        int idx = tid + it*256;
        int c = idx>>2, kq = (idx&3)*8;
        u16x8 v = {};
        if (c0+c < NC) v = *reinterpret_cast<const u16x8*>(Bp + (long)(c0+c)*ldb + (k0+kq));
        *reinterpret_cast<u16x8*>(&Bsm[c][kq]) = v;
      }
    } else {
      #pragma unroll
      for (int it=0; it<2; ++it){
        int idx = tid + it*256;
        int k = idx>>4, cq = (idx&15)*8;
        u16x8 v = {};
        if (c0+cq < NC) v = *reinterpret_cast<const u16x8*>(Bp + (long)(k0+k)*ldb + (c0+cq));
        #pragma unroll
        for (int i=0;i<8;i++) Bsm[cq+i][k] = v[i];
      }
    }
    __syncthreads();
    bf16x8 af[4], bfr[4];
    #pragma unroll
    for (int m=0;m<4;m++) af[m] = *reinterpret_cast<const bf16x8*>(&Asm[wr*64+m*16+lr][lg*8]);
    #pragma unroll
    for (int n=0;n<4;n++) bfr[n] = *reinterpret_cast<const bf16x8*>(&Bsm[wc*64+n*16+lr][lg*8]);
    #pragma unroll
    for (int m=0;m<4;m++)
      #pragma unroll
      for (int n=0;n<4;n++)
        acc[m][n] = __builtin_amdgcn_mfma_f32_16x16x32_bf16(af[m], bfr[n], acc[m][n], 0, 0, 0);
    __syncthreads();
  }

  float* Cf = (float*)C;
  unsigned short* Cb16 = (unsigned short*)C;
  const long coff = (long)b*Cb + (long)h*Ch;
  #pragma unroll
  for (int m=0;m<4;m++){
    #pragma unroll
    for (int n=0;n<4;n++){
      #pragma unroll
      for (int e=0;e<4;e++){
        int r = wr*64 + m*16 + lg*4 + e;   // row = (lane>>4)*4 + reg
        int c = wc*64 + n*16 + lr;         // col = lane&15
        int gr = r0 + r, gc = c0 + c;
        if (gr < R && gc < NC){
          float v = acc[m][n][e] * alpha;
          if (EPI >= 2) v += bias[gc];
          if (EPI == 2) v = gelu_tanh(v);
          if (rowscale) v *= rowscale[(long)bz*rsn + gr];
          if (EPI == 3) v += res[(long)gr*ldc + gc];
          long o = coff + (long)gr*ldc + gc;
          if (OUT_BF16) Cb16[o] = f2b(v); else Cf[o] = v;
        }
      }
    }
  }
}

// ---------------- diag: 0.5*dn^2*||row||^2 from bf16 Q/K ----------------
__global__ __launch_bounds__(256) void k_diag(const unsigned short* __restrict__ src,
    float* __restrict__ out, int rows, int n, int I, int dh, int H, float dn)
{
  int row = blockIdx.x*4 + (threadIdx.x >> 6);
  int lane = threadIdx.x & 63;
  if (row >= rows) return;
  int ni = row % n; int bhh = row / n; int h = bhh % H; int b = bhh / H;
  const unsigned short* p = src + ((long)(b*n + ni))*I + h*dh;
  float s = 0.f;
  for (int i=lane;i<dh;i+=64){ float v=b2f(p[i]); s += v*v; }
  s = wave_sum(s);
  if (lane==0) out[row] = 0.5f*dn*dn*s;
}

// ---------------- global max (2-pass) over fp32 DD ----------------
__global__ __launch_bounds__(256) void k_gmax1(const float* __restrict__ PP,
    float* __restrict__ red, long count)
{
  float mx = -INFINITY;
  for (long i = (long)blockIdx.x*256 + threadIdx.x; i < count; i += (long)gridDim.x*256)
    mx = fmaxf(mx, PP[i]);
  __shared__ float sm[4];
  int lane = threadIdx.x & 63, wid = threadIdx.x >> 6;
  mx = wave_max(mx);
  if (lane==0) sm[wid]=mx;
  __syncthreads();
  if (threadIdx.x==0) red[blockIdx.x] = fmaxf(fmaxf(sm[0],sm[1]), fmaxf(sm[2],sm[3]));
}
__global__ __launch_bounds__(256) void k_gmax2(const float* __restrict__ red,
    float* __restrict__ out, int cnt)
{
  float mx = -INFINITY;
  for (int i=threadIdx.x;i<cnt;i+=256) mx = fmaxf(mx, red[i]);
  __shared__ float sm[4];
  int lane = threadIdx.x & 63, wid = threadIdx.x >> 6;
  mx = wave_max(mx);
  if (lane==0) sm[wid]=mx;
  __syncthreads();
  if (threadIdx.x==0) out[0] = fmaxf(fmaxf(sm[0],sm[1]), fmaxf(sm[2],sm[3]));
}

// ---------------- per-row max over DD rows (stride Mp; pads are 0) ----------------
__global__ __launch_bounds__(256) void k_rowmax(const float* __restrict__ PP,
    float* __restrict__ out, int rows, int Mp)
{
  int row = blockIdx.x*4 + (threadIdx.x >> 6);
  int lane = threadIdx.x & 63;
  if (row >= rows) return;
  const float* p = PP + (long)row*Mp;
  float mx = -INFINITY;
  for (int i=lane;i<Mp;i+=64) mx = fmaxf(mx, p[i]);
  mx = wave_max(mx);
  if (lane==0) out[row] = mx;
}

// ---------------- exp: DD f32 -> bf16 PP; pad cols -> 0 ----------------
template<bool PERROW>
__global__ __launch_bounds__(256) void k_exp2(const float* __restrict__ DD,
    unsigned short* __restrict__ PPb,
    const float* __restrict__ diag, const float* __restrict__ stab,
    long count4, int M, int Mp, float ratio, float eps)
{
  long t = (long)blockIdx.x*256 + threadIdx.x;
  if (t >= count4) return;
  long idx = t*4;
  long row = idx / Mp; int col = (int)(idx % Mp);
  float st = PERROW ? stab[row] : stab[0];
  float dg = diag[row];
  float4 dv = *reinterpret_cast<const float4*>(DD + idx);
  float vv[4] = {dv.x, dv.y, dv.z, dv.w};
  u16x4 ov;
  #pragma unroll
  for (int j=0;j<4;j++){
    float v = (col+j < M) ? ratio*(expf(vv[j]-dg-st)+eps) : 0.0f;
    ov[j] = f2b(v);
  }
  *reinterpret_cast<u16x4*>(PPb + idx) = ov;
}

// ---------------- column sum over n: kpsum[bh,m] = sum_n kp[bh,n,m] ----------------
__global__ __launch_bounds__(256) void k_colsum(const unsigned short* __restrict__ PP,
    float* __restrict__ out, int BH, int n, int Mp)
{
  int idx = blockIdx.x*256 + threadIdx.x;
  if (idx >= BH*Mp) return;
  int bh = idx / Mp, m = idx - bh*Mp;
  const unsigned short* p = PP + (long)bh*n*Mp + m;
  float s = 0.f;
  for (int i=0;i<n;i++) s += b2f(p[(long)i*Mp]);
  out[idx] = s;
}

// ---------------- dinv[row] = 1 / dot(qp[row,:], kpsum[bh,:]) ----------------
__global__ __launch_bounds__(256) void k_dinv(const unsigned short* __restrict__ QP,
    const float* __restrict__ ksum, float* __restrict__ dinv, int rows, int n, int Mp)
{
  int row = blockIdx.x*4 + (threadIdx.x >> 6);
  int lane = threadIdx.x & 63;
  if (row >= rows) return;
  int bh = row / n;
  const unsigned short* q = QP + (long)row*Mp;
  const float* k = ksum + (long)bh*Mp;
  float s = 0.f;
  for (int i=lane;i<Mp;i+=64) s = fmaf(b2f(q[i]), k[i], s);
  s = wave_sum(s);
  if (lane==0) dinv[row] = 1.0f/s;
}

// ---------------- final mean over s ----------------
__global__ __launch_bounds__(256) void k_mean(const float* __restrict__ X,
    float* __restrict__ out)
{
  int idx = blockIdx.x*256 + threadIdx.x;   // b*128+f
  int f = idx & 127, b = idx >> 7;
  const float* p = X + (long)b*256*128 + f;
  float s = 0.f;
  for (int i=0;i<256;i++) s += p[i*128];
  out[idx] = s*(1.0f/256.0f);
}

// ---------------- host-side stage driver ----------------
struct StageP {
  const float *ln1w,*ln1b,*wob,*ln2w,*ln2b,*f1b,*f2b;
  const unsigned short *wqT,*wkT,*wvT,*woT,*f1T,*f2T,*projb;
  int n, D, H, dh, I, M, Mp;
};

static void run_stage(const StageP& P, float* X, unsigned short* LNb,
    unsigned short* Qb, unsigned short* Kb, unsigned short* Vb,
    float* DD, unsigned short* KPb, unsigned short* QPb, unsigned short* CTXT,
    unsigned short* ATTNb, unsigned short* FFHb,
    float* KPSUM, float* DIAG, float* ROWMAX, float* DINV, float* RED,
    hipStream_t stream)
{
  const int B = 64;
  const int rows = B*P.n;
  const int bh = B*P.H;
  const long ppcount = (long)bh*P.n*P.Mp;
  const float dn = powf((float)P.dh, -0.25f);
  const float ratio = 1.0f/sqrtf((float)P.M);

  for (int l=0;l<4;l++){
    const float* ln1w = P.ln1w + (long)l*P.D;
    const float* ln1b = P.ln1b + (long)l*P.D;
    const float* wob  = P.wob  + (long)l*P.D;
    const float* ln2w = P.ln2w + (long)l*P.D;
    const float* ln2b = P.ln2b + (long)l*P.D;
    const float* f1b  = P.f1b  + (long)l*4*P.D;
    const float* f2b_ = P.f2b  + (long)l*P.D;
    const unsigned short* wqT = P.wqT + (long)l*P.D*P.I;
    const unsigned short* wkT = P.wkT + (long)l*P.D*P.I;
    const unsigned short* wvT = P.wvT + (long)l*P.D*P.I;
    const unsigned short* woT = P.woT + (long)l*P.I*P.D;
    const unsigned short* f1T = P.f1T + (long)l*P.D*4*P.D;
    const unsigned short* f2T = P.f2T + (long)l*4*P.D*P.D;
    const unsigned short* pjb = P.projb + (long)l*P.Mp*P.dh;

    k_ln<<<dim3((rows+3)/4),dim3(256),0,stream>>>(X, ln1w, ln1b, LNb, rows, P.D);
    dim3 gq((P.I+127)/128, (rows+127)/128, 1);
    k_mgemm<false,true,0,true><<<gq,dim3(256),0,stream>>>(LNb, wqT, Qb, nullptr,nullptr,nullptr,
        1.f, 1, rows, P.I, P.D, 0,0,(long)P.D, 0,0,(long)P.D, 0,0,(long)P.I, 0);
    k_mgemm<false,true,0,true><<<gq,dim3(256),0,stream>>>(LNb, wkT, Kb, nullptr,nullptr,nullptr,
        1.f, 1, rows, P.I, P.D, 0,0,(long)P.D, 0,0,(long)P.D, 0,0,(long)P.I, 0);
    k_mgemm<false,true,0,true><<<gq,dim3(256),0,stream>>>(LNb, wvT, Vb, nullptr,nullptr,nullptr,
        1.f, 1, rows, P.I, P.D, 0,0,(long)P.D, 0,0,(long)P.D, 0,0,(long)P.I, 0);

    // dd_k -> DD (fp32). A = Kb slice [n,dh] (row-major, lda=I); B = projbf (col-major BT, ldb=dh)
    dim3 gdd((P.Mp+127)/128, (P.n+127)/128, bh);
    k_mgemm<false,true,0,false><<<gdd,dim3(256),0,stream>>>(Kb, pjb, DD, nullptr,nullptr,nullptr,
        dn, P.H, P.n, P.Mp, P.dh,
        (long)P.n*P.I, (long)P.dh, (long)P.I,
        0, 0, (long)P.dh,
        (long)P.H*P.n*P.Mp, (long)P.n*P.Mp, (long)P.Mp, 0);
    k_diag<<<dim3((bh*P.n+3)/4),dim3(256),0,stream>>>(Kb, DIAG, bh*P.n, P.n, P.I, P.dh, P.H, dn);
    k_gmax1<<<dim3(2048),dim3(256),0,stream>>>(DD, RED, ppcount);
    k_gmax2<<<dim3(1),dim3(256),0,stream>>>(RED, RED+2048, 2048);
    k_exp2<false><<<dim3((int)((ppcount/4+255)/256)),dim3(256),0,stream>>>(DD, KPb, DIAG, RED+2048,
        ppcount/4, P.M, P.Mp, ratio, 1e-4f);
    // CTXT = V^T @ kp : R=dh, NC=Mp, K=n. A = V^T (col-major, lda=I); B = kp (row-major, ldb=Mp)
    dim3 gctx((P.Mp+127)/128, (P.dh+127)/128, bh);
    k_mgemm<true,false,0,true><<<gctx,dim3(256),0,stream>>>(Vb, KPb, CTXT, nullptr,nullptr,nullptr,
        1.f, P.H, P.dh, P.Mp, P.n,
        (long)P.n*P.I, (long)P.dh, (long)P.I,
        (long)P.H*P.n*P.Mp, (long)P.n*P.Mp, (long)P.Mp,
        (long)P.H*P.dh*P.Mp, (long)P.dh*P.Mp, (long)P.Mp, 0);
    k_colsum<<<dim3((bh*P.Mp+255)/256),dim3(256),0,stream>>>(KPb, KPSUM, bh, P.n, P.Mp);
    // dd_q -> DD
    k_mgemm<false,true,0,false><<<gdd,dim3(256),0,stream>>>(Qb, pjb, DD, nullptr,nullptr,nullptr,
        dn, P.H, P.n, P.Mp, P.dh,
        (long)P.n*P.I, (long)P.dh, (long)P.I,
        0, 0, (long)P.dh,
        (long)P.H*P.n*P.Mp, (long)P.n*P.Mp, (long)P.Mp, 0);
    k_diag<<<dim3((bh*P.n+3)/4),dim3(256),0,stream>>>(Qb, DIAG, bh*P.n, P.n, P.I, P.dh, P.H, dn);
    k_rowmax<<<dim3((bh*P.n+3)/4),dim3(256),0,stream>>>(DD, ROWMAX, bh*P.n, P.Mp);
    k_exp2<true><<<dim3((int)((ppcount/4+255)/256)),dim3(256),0,stream>>>(DD, QPb, DIAG, ROWMAX,
        ppcount/4, P.M, P.Mp, ratio, 1e-4f);
    k_dinv<<<dim3((bh*P.n+3)/4),dim3(256),0,stream>>>(QPb, KPSUM, DINV, bh*P.n, P.n, P.Mp);
    // out = (qp @ ctx) * dinv -> ATTNb. A = qp (row-major lda=Mp); B = CTXT (col-major ldb=Mp)
    dim3 gout((P.dh+127)/128, (P.n+127)/128, bh);
    k_mgemm<false,true,0,true><<<gout,dim3(256),0,stream>>>(QPb, CTXT, ATTNb, nullptr,nullptr,DINV,
        1.f, P.H, P.n, P.dh, P.Mp,
        (long)P.H*P.n*P.Mp, (long)P.n*P.Mp, (long)P.Mp,
        (long)P.H*P.dh*P.Mp, (long)P.dh*P.Mp, (long)P.Mp,
        (long)P.n*P.I, (long)P.dh, (long)P.I, P.n);
    // x = x + attn @ wo + wob
    dim3 gwo((P.D+127)/128, (rows+127)/128, 1);
    k_mgemm<false,true,3,false><<<gwo,dim3(256),0,stream>>>(ATTNb, woT, X, wob, X, nullptr,
        1.f, 1, rows, P.D, P.I, 0,0,(long)P.I, 0,0,(long)P.I, 0,0,(long)P.D, 0);
    // ff
    k_ln<<<dim3((rows+3)/4),dim3(256),0,stream>>>(X, ln2w, ln2b, LNb, rows, P.D);
    dim3 gf1((4*P.D+127)/128, (rows+127)/128, 1);
    k_mgemm<false,true,2,true><<<gf1,dim3(256),0,stream>>>(LNb, f1T, FFHb, f1b, nullptr, nullptr,
        1.f, 1, rows, 4*P.D, P.D, 0,0,(long)P.D, 0,0,(long)P.D, 0,0,(long)(4*P.D), 0);
    dim3 gf2((P.D+127)/128, (rows+127)/128, 1);
    k_mgemm<false,true,3,false><<<gf2,dim3(256),0,stream>>>(FFHb, f2T, X, f2b_, X, nullptr,
        1.f, 1, rows, P.D, 4*P.D, 0,0,(long)(4*P.D), 0,0,(long)(4*P.D), 0,0,(long)P.D, 0);
  }
}

// ---------------- entry ----------------
extern "C" void kernel_launch(void* const* d_in, const int* in_sizes, int n_in,
                              void* d_out, int out_size, void* d_ws, size_t ws_size,
                              hipStream_t stream)
{
  const float* x     = (const float*)d_in[0];
  const float* lin_w = (const float*)d_in[1];
  const float* lin_b = (const float*)d_in[2];

  // workspace (byte offsets, 256B aligned)
  char* wsb = (char*)d_ws;
  size_t off = 0;
  auto alloc = [&](size_t bytes)->void*{ void* p = wsb + off; off += (bytes + 255) & ~(size_t)255; return p; };
  float* X     = (float*)alloc(8388608);
  float* X2    = (float*)alloc(8388608);
  unsigned short* LNb   = (unsigned short*)alloc(4194304);
  unsigned short* Qb    = (unsigned short*)alloc(10485760);
  unsigned short* Kb    = (unsigned short*)alloc(10485760);
  unsigned short* Vb    = (unsigned short*)alloc(10485760);
  float* DD    = (float*)alloc(104857600);
  unsigned short* KPb   = (unsigned short*)alloc(52428800);
  unsigned short* QP_FFH= (unsigned short*)alloc(52428800);   // QPb during attn, FFH during FF
  unsigned short* CTXT  = (unsigned short*)alloc(52428800);
  unsigned short* ATTNb = (unsigned short*)alloc(10485760);
  unsigned short* WQ1T  = (unsigned short*)alloc(1310720);
  unsigned short* WK1T  = (unsigned short*)alloc(1310720);
  unsigned short* WV1T  = (unsigned short*)alloc(1310720);
  unsigned short* WO1T  = (unsigned short*)alloc(1310720);
  unsigned short* F11T  = (unsigned short*)alloc(2097152);
  unsigned short* F21T  = (unsigned short*)alloc(2097152);
  unsigned short* WQ2T  = (unsigned short*)alloc(262144);
  unsigned short* WK2T  = (unsigned short*)alloc(262144);
  unsigned short* WV2T  = (unsigned short*)alloc(262144);
  unsigned short* WO2T  = (unsigned short*)alloc(262144);
  unsigned short* F12T  = (unsigned short*)alloc(524288);
  unsigned short* F22T  = (unsigned short*)alloc(524288);
  unsigned short* PJ1   = (unsigned short*)alloc(655360);
  unsigned short* PJ2   = (unsigned short*)alloc(147456);
  float* KPSUM = (float*)alloc(819200);
  float* DIAG  = (float*)alloc(262144);
  float* ROWMAX= (float*)alloc(262144);
  float* DINV  = (float*)alloc(262144);
  float* RED   = (float*)alloc(8256);
  if (ws_size < off) return;

  // ---- weight conversions (per call; cheap) ----
  // stage 1: D=256, I=640, 4D=1024
  k_wt<<<dim3(640/32,256/32,4),dim3(256),0,stream>>>((const float*)d_in[5],  WQ1T, 256, 640);
  k_wt<<<dim3(640/32,256/32,4),dim3(256),0,stream>>>((const float*)d_in[6],  WK1T, 256, 640);
  k_wt<<<dim3(640/32,256/32,4),dim3(256),0,stream>>>((const float*)d_in[7],  WV1T, 256, 640);
  k_wt<<<dim3(256/32,640/32,4),dim3(256),0,stream>>>((const float*)d_in[8],  WO1T, 640, 256);
  k_wt<<<dim3(1024/32,256/32,4),dim3(256),0,stream>>>((const float*)d_in[12], F11T, 256, 1024);
  k_wt<<<dim3(256/32,1024/32,4),dim3(256),0,stream>>>((const float*)d_in[14], F21T, 1024, 256);
  // stage 2: D=128, I=256, 4D=512
  k_wt<<<dim3(256/32,128/32,4),dim3(256),0,stream>>>((const float*)d_in[19], WQ2T, 128, 256);
  k_wt<<<dim3(256/32,128/32,4),dim3(256),0,stream>>>((const float*)d_in[20], WK2T, 128, 256);
  k_wt<<<dim3(256/32,128/32,4),dim3(256),0,stream>>>((const float*)d_in[21], WV2T, 128, 256);
  k_wt<<<dim3(128/32,256/32,4),dim3(256),0,stream>>>((const float*)d_in[22], WO2T, 256, 128);
  k_wt<<<dim3(512/32,128/32,4),dim3(256),0,stream>>>((const float*)d_in[26], F12T, 128, 512);
  k_wt<<<dim3(128/32,512/32,4),dim3(256),0,stream>>>((const float*)d_in[28], F22T, 512, 128);
  // proj: stage1 M=620->Mp=640 dh=128 ; stage2 M=266->Mp=288 dh=64
  {
    long t1 = 4L*640*128;
    k_projconv<<<dim3((int)((t1+255)/256)),dim3(256),0,stream>>>((const float*)d_in[16], PJ1, 620, 640, 128, t1);
    long t2 = 4L*288*64;
    k_projconv<<<dim3((int)((t2+255)/256)),dim3(256),0,stream>>>((const float*)d_in[30], PJ2, 266, 288, 64, t2);
  }

  StageP T;
  T.ln1w=(const float*)d_in[3];  T.ln1b=(const float*)d_in[4];
  T.wob=(const float*)d_in[9];
  T.ln2w=(const float*)d_in[10]; T.ln2b=(const float*)d_in[11];
  T.f1b=(const float*)d_in[13];  T.f2b=(const float*)d_in[15];
  T.wqT=WQ1T; T.wkT=WK1T; T.wvT=WV1T; T.woT=WO1T; T.f1T=F11T; T.f2T=F21T; T.projb=PJ1;
  T.n=128; T.D=256; T.H=5; T.dh=128; T.I=640; T.M=620; T.Mp=640;

  StageP Ms;
  Ms.ln1w=(const float*)d_in[17]; Ms.ln1b=(const float*)d_in[18];
  Ms.wob=(const float*)d_in[23];
  Ms.ln2w=(const float*)d_in[24]; Ms.ln2b=(const float*)d_in[25];
  Ms.f1b=(const float*)d_in[27];  Ms.f2b=(const float*)d_in[29];
  Ms.wqT=WQ2T; Ms.wkT=WK2T; Ms.wvT=WV2T; Ms.woT=WO2T; Ms.f1T=F12T; Ms.f2T=F22T; Ms.projb=PJ2;
  Ms.n=256; Ms.D=128; Ms.H=4; Ms.dh=64; Ms.I=256; Ms.M=266; Ms.Mp=288;

  k_embed<<<dim3(8192),dim3(256),0,stream>>>(x, lin_w, lin_b, X);
  run_stage(T, X, LNb, Qb, Kb, Vb, DD, KPb, QP_FFH, CTXT, ATTNb, QP_FFH,
            KPSUM, DIAG, ROWMAX, DINV, RED, stream);
  k_transpose_pe<<<dim3(8192),dim3(256),0,stream>>>(X, X2);
  run_stage(Ms, X2, LNb, Qb, Kb, Vb, DD, KPb, QP_FFH, CTXT, ATTNb, QP_FFH,
            KPSUM, DIAG, ROWMAX, DINV, RED, stream);
  k_mean<<<dim3(32),dim3(256),0,stream>>>(X2, (float*)d_out);
}

// Round 4
// 3965.310 us; speedup vs baseline: 2.5574x; 1.0661x over previous
//
#include <hip/hip_runtime.h>
#include <math.h>

using bf16x8 = __attribute__((ext_vector_type(8))) short;
using f32x4  = __attribute__((ext_vector_type(4))) float;
using u16x8  = __attribute__((ext_vector_type(8))) unsigned short;

__device__ __forceinline__ float b2f(unsigned short u){
  union{float f; unsigned int i;} x; x.i = ((unsigned int)u)<<16; return x.f;
}
__device__ __forceinline__ unsigned short f2b(float f){
  union{float f; unsigned int i;} x; x.f = f;
  unsigned int r = x.i + 0x7fffu + ((x.i>>16)&1u);
  return (unsigned short)(r>>16);
}
__device__ __forceinline__ float gelu_tanh(float x){
  float x3 = x*x*x;
  return 0.5f*x*(1.0f + tanhf(0.79788456080286535588f*(x + 0.044715f*x3)));
}
__device__ __forceinline__ float wave_sum(float v){
  #pragma unroll
  for (int o=32;o>0;o>>=1) v += __shfl_down(v,o);
  return v;
}
__device__ __forceinline__ float wave_max(float v){
  #pragma unroll
  for (int o=32;o>0;o>>=1) v = fmaxf(v, __shfl_down(v,o));
  return v;
}
// monotone float<->uint encoding for atomic max (init 0 < any encoded value we produce)
__device__ __forceinline__ unsigned encmax(float f){
  union{float f; unsigned u;} x; x.f = f;
  return (x.u & 0x80000000u) ? ~x.u : (x.u | 0x80000000u);
}
__device__ __forceinline__ float decmax(unsigned e){
  union{unsigned u; float f;} x;
  x.u = (e & 0x80000000u) ? (e & 0x7fffffffu) : ~e;
  return x.f;
}

// ---------------- embed: per-file linear + transpose + PE(F,S) ----------------
__global__ __launch_bounds__(256) void k_embed(const float* __restrict__ x,
    const float* __restrict__ lw, const float* __restrict__ lb,
    float* __restrict__ X)
{
  int idx = blockIdx.x*256 + threadIdx.x;      // (b*128+f)*256+s
  int s = idx & 255;
  int f = (idx >> 8) & 127;
  int b = idx >> 15;
  const float* xr = x + ((long)(b*256 + s))*2048 + f*16;
  const float* wr = lw + f*16;
  float acc = lb[f];
  #pragma unroll
  for (int c=0;c<16;c++) acc = fmaf(xr[c], wr[c], acc);
  int i = s >> 1;
  float dv = expf((float)(2*i) * (-9.210340371976184f/256.0f));
  float ang = (float)f * dv;
  acc += (s & 1) ? cosf(ang) : sinf(ang);
  X[idx] = acc;
}

// ---------------- transpose [B,128,256]->[B,256,128] + PE(S,F) ----------------
__global__ __launch_bounds__(256) void k_transpose_pe(const float* __restrict__ X,
    float* __restrict__ Y)
{
  int idx = blockIdx.x*256 + threadIdx.x;      // (b*256+s)*128+f
  int f = idx & 127;
  int s = (idx >> 7) & 255;
  int b = idx >> 15;
  int i = f >> 1;
  float dv = expf((float)(2*i) * (-9.210340371976184f/128.0f));
  float ang = (float)s * dv;
  float pe = (f & 1) ? cosf(ang) : sinf(ang);
  Y[idx] = X[((long)(b*128 + f))*256 + s] + pe;
}

// ---------------- layernorm: fp32 in -> bf16 out ----------------
__global__ __launch_bounds__(256) void k_ln(const float* __restrict__ X,
    const float* __restrict__ w, const float* __restrict__ b,
    unsigned short* __restrict__ Y, int R, int D)
{
  int row = blockIdx.x*4 + (threadIdx.x >> 6);
  int lane = threadIdx.x & 63;
  if (row >= R) return;
  const float* xr = X + (long)row*D;
  float sum=0.f, sq=0.f;
  for (int i=lane;i<D;i+=64){ float v=xr[i]; sum+=v; sq+=v*v; }
  sum = wave_sum(sum); sq = wave_sum(sq);
  sum = __shfl(sum,0); sq = __shfl(sq,0);
  float mu = sum/(float)D;
  float var = sq/(float)D - mu*mu;
  float inv = rsqrtf(var + 1e-5f);
  unsigned short* yr = Y + (long)row*D;
  for (int i=lane;i<D;i+=64) yr[i] = f2b((xr[i]-mu)*inv*w[i] + b[i]);
}

// ---------------- weight transpose-convert: W[L][K][N] f32 -> WT bf16 [N][K] at l*lstride ----
__global__ __launch_bounds__(256) void k_wt(const float* __restrict__ W,
    unsigned short* __restrict__ WT, int K, int N, long lstride)
{
  __shared__ float t[32][33];
  int l = blockIdx.z;
  const float* Wp = W + (long)l*K*N;
  unsigned short* Tp = WT + (long)l*lstride;
  int tx = threadIdx.x & 31, ty = threadIdx.x >> 5;
  int kb = blockIdx.y*32, nb = blockIdx.x*32;
  #pragma unroll
  for (int i=0;i<4;i++) t[ty+i*8][tx] = Wp[(long)(kb+ty+i*8)*N + nb+tx];
  __syncthreads();
  #pragma unroll
  for (int i=0;i<4;i++) Tp[(long)(nb+ty+i*8)*K + kb+tx] = f2b(t[tx][ty+i*8]);
}

// ---------------- proj convert + pad: [L][M][dh] f32 -> [L][Mp][dh] bf16 (pad rows zero) ---------
__global__ __launch_bounds__(256) void k_projconv(const float* __restrict__ proj,
    unsigned short* __restrict__ pb, int M, int Mp, int dh, long total)
{
  long idx = (long)blockIdx.x*256 + threadIdx.x;
  if (idx >= total) return;
  int c = (int)(idx % dh);
  long t = idx / dh;
  int m = (int)(t % Mp);
  int l = (int)(t / Mp);
  pb[idx] = (m < M) ? f2b(proj[((long)l*M + m)*dh + c]) : (unsigned short)0;
}

// ---------------- generic MFMA GEMM with fused FAVOR pieces ----------------
// C[R,NC] = alpha * A*B (+bias)(+gelu)(+rowscale)(+res). K multiple of 32.
// EXPA: A is fp32 DD, staged as ratio*(exp(a - diag[row] - dec(stab[row])) + eps), 0 for k>=Mvalid
// EXPB: B is fp32 DD (row-major [K][ldb]), staged as ratio*(exp(b - diag[k] - dec(stab[0])) + eps), 0 for c>=Mvalid
// MAXM: 1 = global atomic max of alpha*acc into maxu[0]; 2 = per-row atomic max into maxu[bz*R+row]
template<bool A_CM, bool B_CM, int EPI, bool OUT_BF16, bool EXPA, bool EXPB, int MAXM>
__global__ __launch_bounds__(256) void k_mgemm(
    const void* __restrict__ A, const void* __restrict__ B, void* __restrict__ C,
    const float* __restrict__ bias, const float* __restrict__ res,
    const float* __restrict__ rowscale,
    const float* __restrict__ ediag, const unsigned* __restrict__ estab,
    unsigned* __restrict__ maxu,
    float ratio, float eps, int Mvalid,
    float alpha, int H, int R, int NC, int K,
    long Ab, long Ah, long lda,
    long Bb, long Bh, long ldb,
    long Cb, long Ch, long ldc, int rsn)
{
  __shared__ unsigned short Asm[128][40];
  __shared__ unsigned short Bsm[128][40];
  __shared__ float sred[4];
  const int tid = threadIdx.x;
  const int bz = blockIdx.z;
  const int b = bz / H, h = bz - b*H;
  const unsigned short* Ap16 = (const unsigned short*)A + (long)b*Ab + (long)h*Ah;
  const unsigned short* Bp16 = (const unsigned short*)B + (long)b*Bb + (long)h*Bh;
  const float* Apf = (const float*)A + (long)b*Ab + (long)h*Ah;
  const float* Bpf = (const float*)B + (long)b*Bb + (long)h*Bh;
  const int r0 = blockIdx.y*128, c0 = blockIdx.x*128;
  const int wid = tid>>6, lane = tid&63;
  const int wr = wid>>1, wc = wid&1;
  const int lr = lane&15, lg = lane>>4;
  float stabB = 0.f;
  if (EXPB) stabB = decmax(estab[0]);
  f32x4 acc[4][4] = {};

  for (int k0=0; k0<K; k0+=32){
    // ---- stage A tile -> Asm[r][k]
    if constexpr (EXPA){
      #pragma unroll
      for (int it=0; it<2; ++it){
        int idx = tid + it*256;
        int r = idx>>2, kq = (idx&3)*8;
        long grow = (long)bz*R + (r0+r);
        float dg = ediag[grow];
        float st = decmax(estab[grow]);
        const float* src = Apf + (long)(r0+r)*lda + (k0+kq);
        float4 v0 = *reinterpret_cast<const float4*>(src);
        float4 v1 = *reinterpret_cast<const float4*>(src+4);
        float vv[8] = {v0.x,v0.y,v0.z,v0.w,v1.x,v1.y,v1.z,v1.w};
        #pragma unroll
        for (int i=0;i<8;i++){
          int kk = k0+kq+i;
          float v = (kk < Mvalid) ? ratio*(expf(vv[i]-dg-st)+eps) : 0.0f;
          Asm[r][kq+i] = f2b(v);
        }
      }
    } else if constexpr (!A_CM){
      #pragma unroll
      for (int it=0; it<2; ++it){
        int idx = tid + it*256;
        int r = idx>>2, kq = (idx&3)*8;
        u16x8 v = *reinterpret_cast<const u16x8*>(Ap16 + (long)(r0+r)*lda + (k0+kq));
        *reinterpret_cast<u16x8*>(&Asm[r][kq]) = v;
      }
    } else {
      #pragma unroll
      for (int it=0; it<2; ++it){
        int idx = tid + it*256;
        int k = idx>>4, rq = (idx&15)*8;
        u16x8 v = {};
        if (r0+rq < R) v = *reinterpret_cast<const u16x8*>(Ap16 + (long)(k0+k)*lda + (r0+rq));
        #pragma unroll
        for (int i=0;i<8;i++) Asm[rq+i][k] = v[i];
      }
    }
    // ---- stage B tile -> Bsm[c][k]
    if constexpr (EXPB){
      #pragma unroll
      for (int it=0; it<2; ++it){
        int idx = tid + it*256;
        int k = idx>>4, cq = (idx&15)*8;
        float dg = ediag[(long)bz*K + (k0+k)];
        float vv[8] = {};
        if (c0+cq < NC){
          const float* src = Bpf + (long)(k0+k)*ldb + (c0+cq);
          float4 v0 = *reinterpret_cast<const float4*>(src);
          float4 v1 = *reinterpret_cast<const float4*>(src+4);
          vv[0]=v0.x; vv[1]=v0.y; vv[2]=v0.z; vv[3]=v0.w;
          vv[4]=v1.x; vv[5]=v1.y; vv[6]=v1.z; vv[7]=v1.w;
        }
        #pragma unroll
        for (int i=0;i<8;i++){
          int c = c0+cq+i;
          float v = (c < Mvalid && c0+cq < NC) ? ratio*(expf(vv[i]-dg-stabB)+eps) : 0.0f;
          Bsm[cq+i][k] = f2b(v);
        }
      }
    } else if constexpr (B_CM){
      #pragma unroll
      for (int it=0; it<2; ++it){
        int idx = tid + it*256;
        int c = idx>>2, kq = (idx&3)*8;
        u16x8 v = {};
        if (c0+c < NC) v = *reinterpret_cast<const u16x8*>(Bp16 + (long)(c0+c)*ldb + (k0+kq));
        *reinterpret_cast<u16x8*>(&Bsm[c][kq]) = v;
      }
    } else {
      #pragma unroll
      for (int it=0; it<2; ++it){
        int idx = tid + it*256;
        int k = idx>>4, cq = (idx&15)*8;
        u16x8 v = {};
        if (c0+cq < NC) v = *reinterpret_cast<const u16x8*>(Bp16 + (long)(k0+k)*ldb + (c0+cq));
        #pragma unroll
        for (int i=0;i<8;i++) Bsm[cq+i][k] = v[i];
      }
    }
    __syncthreads();
    bf16x8 af[4], bfr[4];
    #pragma unroll
    for (int m=0;m<4;m++) af[m] = *reinterpret_cast<const bf16x8*>(&Asm[wr*64+m*16+lr][lg*8]);
    #pragma unroll
    for (int n=0;n<4;n++) bfr[n] = *reinterpret_cast<const bf16x8*>(&Bsm[wc*64+n*16+lr][lg*8]);
    #pragma unroll
    for (int m=0;m<4;m++)
      #pragma unroll
      for (int n=0;n<4;n++)
        acc[m][n] = __builtin_amdgcn_mfma_f32_16x16x32_bf16(af[m], bfr[n], acc[m][n], 0, 0, 0);
    __syncthreads();
  }

  // ---- fused max epilogues
  if constexpr (MAXM==1){
    float mx = -INFINITY;
    #pragma unroll
    for (int m=0;m<4;m++)
      #pragma unroll
      for (int n=0;n<4;n++)
        #pragma unroll
        for (int e=0;e<4;e++) mx = fmaxf(mx, acc[m][n][e]);
    mx *= alpha;
    mx = wave_max(mx);
    if (lane==0) sred[wid]=mx;
    __syncthreads();
    if (tid==0) atomicMax(maxu, encmax(fmaxf(fmaxf(sred[0],sred[1]),fmaxf(sred[2],sred[3]))));
  }
  if constexpr (MAXM==2){
    #pragma unroll
    for (int m=0;m<4;m++){
      #pragma unroll
      for (int e=0;e<4;e++){
        float mx = acc[m][0][e];
        #pragma unroll
        for (int n=1;n<4;n++) mx = fmaxf(mx, acc[m][n][e]);
        mx *= alpha;
        #pragma unroll
        for (int o=1;o<16;o<<=1) mx = fmaxf(mx, __shfl_xor(mx, o));
        if (lr==0){
          int gr = r0 + wr*64 + m*16 + lg*4 + e;
          atomicMax(maxu + (long)bz*R + gr, encmax(mx));
        }
      }
    }
  }

  float* Cf = (float*)C;
  unsigned short* Cb16 = (unsigned short*)C;
  const long coff = (long)b*Cb + (long)h*Ch;
  #pragma unroll
  for (int m=0;m<4;m++){
    #pragma unroll
    for (int n=0;n<4;n++){
      #pragma unroll
      for (int e=0;e<4;e++){
        int r = wr*64 + m*16 + lg*4 + e;
        int c = wc*64 + n*16 + lr;
        int gr = r0 + r, gc = c0 + c;
        if (gr < R && gc < NC){
          float v = acc[m][n][e] * alpha;
          if (EPI >= 2) v += bias[gc];
          if (EPI == 2) v = gelu_tanh(v);
          if (rowscale) v *= rowscale[(long)bz*rsn + gr];
          if (EPI == 3) v += res[(long)gr*ldc + gc];
          long o = coff + (long)gr*ldc + gc;
          if (OUT_BF16) Cb16[o] = f2b(v); else Cf[o] = v;
        }
      }
    }
  }
}

// ---------------- diag for K and Q segments + init ROWMAXU/REDU ----------------
// KQ layout: [K: rows*I][Q: rows*I], rows=B*n. DIAG: [K diag: bhn][Q diag: bhn]
__global__ __launch_bounds__(256) void k_diag2(const unsigned short* __restrict__ KQ,
    float* __restrict__ DIAG, unsigned* __restrict__ ROWMAXU, unsigned* __restrict__ REDU,
    int bhn, int rows, int n, int I, int dh, int H, float dn)
{
  int row = blockIdx.x*4 + (threadIdx.x >> 6);
  int lane = threadIdx.x & 63;
  if (row >= 2*bhn) return;
  int seg = row < bhn ? 0 : 1;
  int r = row - seg*bhn;
  int ni = r % n; int bhh = r / n; int h = bhh % H; int b = bhh / H;
  const unsigned short* p = KQ + (long)seg*rows*I + ((long)(b*n + ni))*I + h*dh;
  float s = 0.f;
  for (int i=lane;i<dh;i+=64){ float v=b2f(p[i]); s += v*v; }
  s = wave_sum(s);
  if (lane==0){
    DIAG[row] = 0.5f*dn*dn*s;
    if (seg==0){
      ROWMAXU[r] = 0u;
      if (r==0) REDU[0] = 0u;
    }
  }
}

// ---------------- column sum with fused exp: kpsum[bh,m] = sum_n kp[bh,n,m] ----------------
__global__ __launch_bounds__(256) void k_colsum2(const float* __restrict__ DDk,
    const float* __restrict__ diagk, const unsigned* __restrict__ REDU,
    float* __restrict__ out, int BH, int n, int Mp, int M, float ratio, float eps)
{
  int idx = blockIdx.x*256 + threadIdx.x;
  if (idx >= BH*Mp) return;
  int bh = idx / Mp, m = idx - bh*Mp;
  if (m >= M){ out[idx] = 0.f; return; }
  float st = decmax(REDU[0]);
  const float* p = DDk + (long)bh*n*Mp + m;
  const float* dg = diagk + (long)bh*n;
  float s = 0.f;
  for (int i=0;i<n;i++) s += expf(p[(long)i*Mp] - dg[i] - st);
  out[idx] = ratio*(s + eps*(float)n);
}

// ---------------- dinv with fused exp: 1 / dot(qp[row,:], kpsum[bh,:]) ----------------
__global__ __launch_bounds__(256) void k_dinv2(const float* __restrict__ DDq,
    const float* __restrict__ diagq, const unsigned* __restrict__ ROWMAXU,
    const float* __restrict__ ksum, float* __restrict__ dinv,
    int rows, int n, int Mp, float ratio, float eps)
{
  int row = blockIdx.x*4 + (threadIdx.x >> 6);
  int lane = threadIdx.x & 63;
  if (row >= rows) return;
  int bh = row / n;
  float dg = diagq[row];
  float st = decmax(ROWMAXU[row]);
  const float* q = DDq + (long)row*Mp;
  const float* k = ksum + (long)bh*Mp;
  float s = 0.f;
  for (int i=lane;i<Mp;i+=64){
    float kv = k[i];
    s += (expf(q[i]-dg-st)+eps) * kv;   // ksum pad cols are 0
  }
  s = wave_sum(s);
  if (lane==0) dinv[row] = 1.0f/(ratio*s);
}

// ---------------- final mean over s ----------------
__global__ __launch_bounds__(256) void k_mean(const float* __restrict__ X,
    float* __restrict__ out)
{
  int idx = blockIdx.x*256 + threadIdx.x;   // b*128+f
  int f = idx & 127, b = idx >> 7;
  const float* p = X + (long)b*256*128 + f;
  float s = 0.f;
  for (int i=0;i<256;i++) s += p[i*128];
  out[idx] = s*(1.0f/256.0f);
}

// ---------------- host-side stage driver ----------------
struct StageP {
  const float *ln1w,*ln1b,*wob,*ln2w,*ln2b,*f1b,*f2b;
  const unsigned short *wkqvT,*woT,*f1T,*f2T,*projb;
  int n, D, H, dh, I, M, Mp;
};

static void run_stage(const StageP& P, float* X, unsigned short* LNb,
    unsigned short* KQVb, float* DDk, float* DDq, unsigned short* CTXT,
    unsigned short* ATTNb, unsigned short* FFHb,
    float* KPSUM, float* DIAG, unsigned* ROWMAXU, float* DINV, unsigned* REDU,
    hipStream_t stream)
{
  const int B = 64;
  const int rows = B*P.n;
  const int bh = B*P.H;
  const int bhn = bh*P.n;
  const float dn = powf((float)P.dh, -0.25f);
  const float ratio = 1.0f/sqrtf((float)P.M);
  const float eps = 1e-4f;

  const unsigned short* Kb = KQVb;                       // K segment first
  const unsigned short* Qb = KQVb + (long)rows*P.I;
  const unsigned short* Vb = KQVb + 2L*rows*P.I;
  const float* DIAGK = DIAG;
  const float* DIAGQ = DIAG + bhn;

  for (int l=0;l<4;l++){
    const float* ln1w = P.ln1w + (long)l*P.D;
    const float* ln1b = P.ln1b + (long)l*P.D;
    const float* wob  = P.wob  + (long)l*P.D;
    const float* ln2w = P.ln2w + (long)l*P.D;
    const float* ln2b = P.ln2b + (long)l*P.D;
    const float* f1b  = P.f1b  + (long)l*4*P.D;
    const float* f2b_ = P.f2b  + (long)l*P.D;
    const unsigned short* wkqvT = P.wkqvT + (long)l*3*P.D*P.I;
    const unsigned short* woT = P.woT + (long)l*P.I*P.D;
    const unsigned short* f1T = P.f1T + (long)l*P.D*4*P.D;
    const unsigned short* f2T = P.f2T + (long)l*4*P.D*P.D;
    const unsigned short* pjb = P.projb + (long)l*P.Mp*P.dh;

    k_ln<<<dim3((rows+3)/4),dim3(256),0,stream>>>(X, ln1w, ln1b, LNb, rows, P.D);
    // fused K,Q,V projection: grid.z selects weight/output segment
    dim3 gq((P.I+127)/128, rows/128, 3);
    k_mgemm<false,true,0,true,false,false,0><<<gq,dim3(256),0,stream>>>(
        LNb, wkqvT, KQVb, nullptr,nullptr,nullptr, nullptr,nullptr,nullptr, 0,0,0,
        1.f, 1, rows, P.I, P.D,
        0,0,(long)P.D,
        (long)P.I*P.D,0,(long)P.D,
        (long)rows*P.I,0,(long)P.I, 0);
    // diag for K and Q + init ROWMAXU/REDU
    k_diag2<<<dim3((2*bhn+3)/4),dim3(256),0,stream>>>(KQVb, DIAG, ROWMAXU, REDU,
        bhn, rows, P.n, P.I, P.dh, P.H, dn);
    // dd_k -> DDk (fp32), fused global max
    dim3 gdd((P.Mp+127)/128, P.n/128, bh);
    k_mgemm<false,true,0,false,false,false,1><<<gdd,dim3(256),0,stream>>>(
        Kb, pjb, DDk, nullptr,nullptr,nullptr, nullptr,nullptr,REDU, 0,0,0,
        dn, P.H, P.n, P.Mp, P.dh,
        (long)P.n*P.I, (long)P.dh, (long)P.I,
        0, 0, (long)P.dh,
        (long)P.H*P.n*P.Mp, (long)P.n*P.Mp, (long)P.Mp, 0);
    // CTXT = V^T @ kp with exp fused on B-stage
    dim3 gctx((P.Mp+127)/128, (P.dh+127)/128, bh);
    k_mgemm<true,false,0,true,false,true,0><<<gctx,dim3(256),0,stream>>>(
        Vb, DDk, CTXT, nullptr,nullptr,nullptr, DIAGK, REDU, nullptr,
        ratio, eps, P.M,
        1.f, P.H, P.dh, P.Mp, P.n,
        (long)P.n*P.I, (long)P.dh, (long)P.I,
        (long)P.H*P.n*P.Mp, (long)P.n*P.Mp, (long)P.Mp,
        (long)P.H*P.dh*P.Mp, (long)P.dh*P.Mp, (long)P.Mp, 0);
    // kpsum (exp fused)
    k_colsum2<<<dim3((bh*P.Mp+255)/256),dim3(256),0,stream>>>(DDk, DIAGK, REDU,
        KPSUM, bh, P.n, P.Mp, P.M, ratio, eps);
    // dd_q -> DDq (fp32), fused row max
    k_mgemm<false,true,0,false,false,false,2><<<gdd,dim3(256),0,stream>>>(
        Qb, pjb, DDq, nullptr,nullptr,nullptr, nullptr,nullptr,ROWMAXU, 0,0,0,
        dn, P.H, P.n, P.Mp, P.dh,
        (long)P.n*P.I, (long)P.dh, (long)P.I,
        0, 0, (long)P.dh,
        (long)P.H*P.n*P.Mp, (long)P.n*P.Mp, (long)P.Mp, 0);
    // dinv (exp fused)
    k_dinv2<<<dim3((bhn+3)/4),dim3(256),0,stream>>>(DDq, DIAGQ, ROWMAXU, KPSUM,
        DINV, bhn, P.n, P.Mp, ratio, eps);
    // out = (qp @ ctx) * dinv, exp fused on A-stage
    dim3 gout((P.dh+127)/128, P.n/128, bh);
    k_mgemm<false,true,0,true,true,false,0><<<gout,dim3(256),0,stream>>>(
        DDq, CTXT, ATTNb, nullptr,nullptr,DINV, DIAGQ, ROWMAXU, nullptr,
        ratio, eps, P.M,
        1.f, P.H, P.n, P.dh, P.Mp,
        (long)P.H*P.n*P.Mp, (long)P.n*P.Mp, (long)P.Mp,
        (long)P.H*P.dh*P.Mp, (long)P.dh*P.Mp, (long)P.Mp,
        (long)P.n*P.I, (long)P.dh, (long)P.I, P.n);
    // x = x + attn @ wo + wob
    dim3 gwo((P.D+127)/128, rows/128, 1);
    k_mgemm<false,true,3,false,false,false,0><<<gwo,dim3(256),0,stream>>>(
        ATTNb, woT, X, wob, X, nullptr, nullptr,nullptr,nullptr, 0,0,0,
        1.f, 1, rows, P.D, P.I, 0,0,(long)P.I, 0,0,(long)P.I, 0,0,(long)P.D, 0);
    // ff
    k_ln<<<dim3((rows+3)/4),dim3(256),0,stream>>>(X, ln2w, ln2b, LNb, rows, P.D);
    dim3 gf1((4*P.D+127)/128, rows/128, 1);
    k_mgemm<false,true,2,true,false,false,0><<<gf1,dim3(256),0,stream>>>(
        LNb, f1T, FFHb, f1b, nullptr, nullptr, nullptr,nullptr,nullptr, 0,0,0,
        1.f, 1, rows, 4*P.D, P.D, 0,0,(long)P.D, 0,0,(long)P.D, 0,0,(long)(4*P.D), 0);
    dim3 gf2((P.D+127)/128, rows/128, 1);
    k_mgemm<false,true,3,false,false,false,0><<<gf2,dim3(256),0,stream>>>(
        FFHb, f2T, X, f2b_, X, nullptr, nullptr,nullptr,nullptr, 0,0,0,
        1.f, 1, rows, P.D, 4*P.D, 0,0,(long)(4*P.D), 0,0,(long)(4*P.D), 0,0,(long)P.D, 0);
  }
}

// ---------------- entry ----------------
extern "C" void kernel_launch(void* const* d_in, const int* in_sizes, int n_in,
                              void* d_out, int out_size, void* d_ws, size_t ws_size,
                              hipStream_t stream)
{
  const float* x     = (const float*)d_in[0];
  const float* lin_w = (const float*)d_in[1];
  const float* lin_b = (const float*)d_in[2];

  char* wsb = (char*)d_ws;
  size_t off = 0;
  auto alloc = [&](size_t bytes)->void*{ void* p = wsb + off; off += (bytes + 255) & ~(size_t)255; return p; };
  float* X     = (float*)alloc(8388608);
  float* X2    = (float*)alloc(8388608);
  unsigned short* LNb   = (unsigned short*)alloc(4194304);
  unsigned short* KQVb  = (unsigned short*)alloc(31457280);   // [K][Q][V] bf16
  float* DDk   = (float*)alloc(104857600);
  float* DDq   = (float*)alloc(104857600);
  unsigned short* CTXT  = (unsigned short*)alloc(52428800);
  unsigned short* ATTNb = (unsigned short*)alloc(10485760);
  unsigned short* WKQV1 = (unsigned short*)alloc(3932160);    // [L][3][I][D]
  unsigned short* WO1T  = (unsigned short*)alloc(1310720);
  unsigned short* F11T  = (unsigned short*)alloc(2097152);
  unsigned short* F21T  = (unsigned short*)alloc(2097152);
  unsigned short* WKQV2 = (unsigned short*)alloc(786432);
  unsigned short* WO2T  = (unsigned short*)alloc(262144);
  unsigned short* F12T  = (unsigned short*)alloc(524288);
  unsigned short* F22T  = (unsigned short*)alloc(524288);
  unsigned short* PJ1   = (unsigned short*)alloc(655360);
  unsigned short* PJ2   = (unsigned short*)alloc(147456);
  float* KPSUM = (float*)alloc(819200);
  float* DIAG  = (float*)alloc(524288);
  unsigned* ROWMAXU = (unsigned*)alloc(262144);
  float* DINV  = (float*)alloc(262144);
  unsigned* REDU = (unsigned*)alloc(256);
  unsigned short* FFHb = (unsigned short*)DDk;   // FF hidden aliases DDk (dead during FF)
  if (ws_size < off) return;

  // ---- weight conversions: pack K,Q,V contiguously per layer ----
  // stage 1: D=256, I=640 (N=I, K=D for fwd weights)
  k_wt<<<dim3(640/32,256/32,4),dim3(256),0,stream>>>((const float*)d_in[6],  WKQV1+0L*640*256, 256, 640, 3L*640*256);
  k_wt<<<dim3(640/32,256/32,4),dim3(256),0,stream>>>((const float*)d_in[5],  WKQV1+1L*640*256, 256, 640, 3L*640*256);
  k_wt<<<dim3(640/32,256/32,4),dim3(256),0,stream>>>((const float*)d_in[7],  WKQV1+2L*640*256, 256, 640, 3L*640*256);
  k_wt<<<dim3(256/32,640/32,4),dim3(256),0,stream>>>((const float*)d_in[8],  WO1T, 640, 256, 640L*256);
  k_wt<<<dim3(1024/32,256/32,4),dim3(256),0,stream>>>((const float*)d_in[12], F11T, 256, 1024, 1024L*256);
  k_wt<<<dim3(256/32,1024/32,4),dim3(256),0,stream>>>((const float*)d_in[14], F21T, 1024, 256, 1024L*256);
  // stage 2: D=128, I=256
  k_wt<<<dim3(256/32,128/32,4),dim3(256),0,stream>>>((const float*)d_in[20], WKQV2+0L*256*128, 128, 256, 3L*256*128);
  k_wt<<<dim3(256/32,128/32,4),dim3(256),0,stream>>>((const float*)d_in[19], WKQV2+1L*256*128, 128, 256, 3L*256*128);
  k_wt<<<dim3(256/32,128/32,4),dim3(256),0,stream>>>((const float*)d_in[21], WKQV2+2L*256*128, 128, 256, 3L*256*128);
  k_wt<<<dim3(128/32,256/32,4),dim3(256),0,stream>>>((const float*)d_in[22], WO2T, 256, 128, 256L*128);
  k_wt<<<dim3(512/32,128/32,4),dim3(256),0,stream>>>((const float*)d_in[26], F12T, 128, 512, 512L*128);
  k_wt<<<dim3(128/32,512/32,4),dim3(256),0,stream>>>((const float*)d_in[28], F22T, 512, 128, 512L*128);
  {
    long t1 = 4L*640*128;
    k_projconv<<<dim3((int)((t1+255)/256)),dim3(256),0,stream>>>((const float*)d_in[16], PJ1, 620, 640, 128, t1);
    long t2 = 4L*288*64;
    k_projconv<<<dim3((int)((t2+255)/256)),dim3(256),0,stream>>>((const float*)d_in[30], PJ2, 266, 288, 64, t2);
  }

  StageP T;
  T.ln1w=(const float*)d_in[3];  T.ln1b=(const float*)d_in[4];
  T.wob=(const float*)d_in[9];
  T.ln2w=(const float*)d_in[10]; T.ln2b=(const float*)d_in[11];
  T.f1b=(const float*)d_in[13];  T.f2b=(const float*)d_in[15];
  T.wkqvT=WKQV1; T.woT=WO1T; T.f1T=F11T; T.f2T=F21T; T.projb=PJ1;
  T.n=128; T.D=256; T.H=5; T.dh=128; T.I=640; T.M=620; T.Mp=640;

  StageP Ms;
  Ms.ln1w=(const float*)d_in[17]; Ms.ln1b=(const float*)d_in[18];
  Ms.wob=(const float*)d_in[23];
  Ms.ln2w=(const float*)d_in[24]; Ms.ln2b=(const float*)d_in[25];
  Ms.f1b=(const float*)d_in[27];  Ms.f2b=(const float*)d_in[29];
  Ms.wkqvT=WKQV2; Ms.woT=WO2T; Ms.f1T=F12T; Ms.f2T=F22T; Ms.projb=PJ2;
  Ms.n=256; Ms.D=128; Ms.H=4; Ms.dh=64; Ms.I=256; Ms.M=266; Ms.Mp=288;

  k_embed<<<dim3(8192),dim3(256),0,stream>>>(x, lin_w, lin_b, X);
  run_stage(T, X, LNb, KQVb, DDk, DDq, CTXT, ATTNb, FFHb,
            KPSUM, DIAG, ROWMAXU, DINV, REDU, stream);
  k_transpose_pe<<<dim3(8192),dim3(256),0,stream>>>(X, X2);
  run_stage(Ms, X2, LNb, KQVb, DDk, DDq, CTXT, ATTNb, FFHb,
            KPSUM, DIAG, ROWMAXU, DINV, REDU, stream);
  k_mean<<<dim3(32),dim3(256),0,stream>>>(X2, (float*)d_out);
}

// Round 5
// 2987.149 us; speedup vs baseline: 3.3948x; 1.3275x over previous
//
#include <hip/hip_runtime.h>
#include <math.h>

using bf16x8 = __attribute__((ext_vector_type(8))) short;
using f32x4  = __attribute__((ext_vector_type(4))) float;
using u16x8  = __attribute__((ext_vector_type(8))) unsigned short;

__device__ __forceinline__ float b2f(unsigned short u){
  union{float f; unsigned int i;} x; x.i = ((unsigned int)u)<<16; return x.f;
}
__device__ __forceinline__ unsigned short f2b(float f){
  union{float f; unsigned int i;} x; x.f = f;
  unsigned int r = x.i + 0x7fffu + ((x.i>>16)&1u);
  return (unsigned short)(r>>16);
}
__device__ __forceinline__ float gelu_tanh(float x){
  float x3 = x*x*x;
  return 0.5f*x*(1.0f + tanhf(0.79788456080286535588f*(x + 0.044715f*x3)));
}
__device__ __forceinline__ float wave_sum(float v){
  #pragma unroll
  for (int o=32;o>0;o>>=1) v += __shfl_down(v,o);
  return v;
}
__device__ __forceinline__ float wave_max(float v){
  #pragma unroll
  for (int o=32;o>0;o>>=1) v = fmaxf(v, __shfl_down(v,o));
  return v;
}
// monotone float<->uint encoding for atomic max (init 0 < any encoded real value)
__device__ __forceinline__ unsigned encmax(float f){
  union{float f; unsigned u;} x; x.f = f;
  return (x.u & 0x80000000u) ? ~x.u : (x.u | 0x80000000u);
}
__device__ __forceinline__ float decmax(unsigned e){
  union{unsigned u; float f;} x;
  x.u = (e & 0x80000000u) ? (e & 0x7fffffffu) : ~e;
  return x.f;
}

// ---------------- embed: per-file linear + transpose + PE(F,S) ----------------
__global__ __launch_bounds__(256) void k_embed(const float* __restrict__ x,
    const float* __restrict__ lw, const float* __restrict__ lb,
    float* __restrict__ X)
{
  int idx = blockIdx.x*256 + threadIdx.x;      // (b*128+f)*256+s
  int s = idx & 255;
  int f = (idx >> 8) & 127;
  int b = idx >> 15;
  const float* xr = x + ((long)(b*256 + s))*2048 + f*16;
  const float* wr = lw + f*16;
  float acc = lb[f];
  #pragma unroll
  for (int c=0;c<16;c++) acc = fmaf(xr[c], wr[c], acc);
  int i = s >> 1;
  float dv = expf((float)(2*i) * (-9.210340371976184f/256.0f));
  float ang = (float)f * dv;
  acc += (s & 1) ? cosf(ang) : sinf(ang);
  X[idx] = acc;
}

// ---------------- transpose [B,128,256]->[B,256,128] + PE(S,F) ----------------
__global__ __launch_bounds__(256) void k_transpose_pe(const float* __restrict__ X,
    float* __restrict__ Y)
{
  int idx = blockIdx.x*256 + threadIdx.x;      // (b*256+s)*128+f
  int f = idx & 127;
  int s = (idx >> 7) & 255;
  int b = idx >> 15;
  int i = f >> 1;
  float dv = expf((float)(2*i) * (-9.210340371976184f/128.0f));
  float ang = (float)s * dv;
  float pe = (f & 1) ? cosf(ang) : sinf(ang);
  Y[idx] = X[((long)(b*128 + f))*256 + s] + pe;
}

// ---------------- layernorm: fp32 in -> bf16 out ----------------
__global__ __launch_bounds__(256) void k_ln(const float* __restrict__ X,
    const float* __restrict__ w, const float* __restrict__ b,
    unsigned short* __restrict__ Y, int R, int D)
{
  int row = blockIdx.x*4 + (threadIdx.x >> 6);
  int lane = threadIdx.x & 63;
  if (row >= R) return;
  const float* xr = X + (long)row*D;
  float sum=0.f, sq=0.f;
  for (int i=lane;i<D;i+=64){ float v=xr[i]; sum+=v; sq+=v*v; }
  sum = wave_sum(sum); sq = wave_sum(sq);
  sum = __shfl(sum,0); sq = __shfl(sq,0);
  float mu = sum/(float)D;
  float var = sq/(float)D - mu*mu;
  float inv = rsqrtf(var + 1e-5f);
  unsigned short* yr = Y + (long)row*D;
  for (int i=lane;i<D;i+=64) yr[i] = f2b((xr[i]-mu)*inv*w[i] + b[i]);
}

// ---------------- weight transpose-convert: W[L][K][N] f32 -> WT bf16 [N][K] at l*lstride ----
__global__ __launch_bounds__(256) void k_wt(const float* __restrict__ W,
    unsigned short* __restrict__ WT, int K, int N, long lstride)
{
  __shared__ float t[32][33];
  int l = blockIdx.z;
  const float* Wp = W + (long)l*K*N;
  unsigned short* Tp = WT + (long)l*lstride;
  int tx = threadIdx.x & 31, ty = threadIdx.x >> 5;
  int kb = blockIdx.y*32, nb = blockIdx.x*32;
  #pragma unroll
  for (int i=0;i<4;i++) t[ty+i*8][tx] = Wp[(long)(kb+ty+i*8)*N + nb+tx];
  __syncthreads();
  #pragma unroll
  for (int i=0;i<4;i++) Tp[(long)(nb+ty+i*8)*K + kb+tx] = f2b(t[tx][ty+i*8]);
}

// ---------------- proj convert + pad: [L][M][dh] f32 -> [L][Mp][dh] bf16 (pad rows zero) ---------
__global__ __launch_bounds__(256) void k_projconv(const float* __restrict__ proj,
    unsigned short* __restrict__ pb, int M, int Mp, int dh, long total)
{
  long idx = (long)blockIdx.x*256 + threadIdx.x;
  if (idx >= total) return;
  int c = (int)(idx % dh);
  long t = idx / dh;
  int m = (int)(t % Mp);
  int l = (int)(t / Mp);
  pb[idx] = (m < M) ? f2b(proj[((long)l*M + m)*dh + c]) : (unsigned short)0;
}

// ---------------- generic MFMA GEMM with fused FAVOR pieces ----------------
// C[R,NC] = alpha * A*B (+bias)(+gelu)(+rowscale)(+res). K multiple of 32.
// EXPA: A is bf16 DD, staged as ratio*(exp(a - diag[row] - dec(stab[row])) + eps), 0 for k>=Mvalid
// EXPB: B is bf16 DD (row-major [K][ldb]), staged as ratio*(exp(b - diag[k] - dec(stab[0])) + eps), 0 for c>=Mvalid
// MAXM: 1 = global atomic max of alpha*acc into maxu[0]; 2 = per-row atomic max into maxu[bz*R+row]
// KSUM (with EXPB): per-column sums of staged B -> ksumio[bz*NC + c]
// QDIV (with EXPA): per-row sum of staged A * ksumio[bz*K + k]; epilogue scales by 1/sum
template<bool A_CM, bool B_CM, int EPI, bool OUT_BF16, bool EXPA, bool EXPB, int MAXM,
         bool KSUM, bool QDIV>
__global__ __launch_bounds__(256) void k_mgemm(
    const void* __restrict__ A, const void* __restrict__ B, void* __restrict__ C,
    const float* __restrict__ bias, const float* __restrict__ res,
    const float* __restrict__ rowscale,
    const float* __restrict__ ediag, const unsigned* __restrict__ estab,
    unsigned* __restrict__ maxu, float* __restrict__ ksumio,
    float ratio, float eps, int Mvalid,
    float alpha, int H, int R, int NC, int K,
    long Ab, long Ah, long lda,
    long Bb, long Bh, long ldb,
    long Cb, long Ch, long ldc, int rsn)
{
  __shared__ unsigned short Asm[128][40];
  __shared__ unsigned short Bsm[128][40];
  __shared__ float sred[4];
  __shared__ float ks_lds[KSUM?16:1][KSUM?132:1];
  __shared__ float qs_lds[QDIV?128:1][QDIV?4:1];
  __shared__ float dinv_lds[QDIV?128:1];
  const int tid = threadIdx.x;
  const int bz = blockIdx.z;
  const int b = bz / H, h = bz - b*H;
  const unsigned short* Ap16 = (const unsigned short*)A + (long)b*Ab + (long)h*Ah;
  const unsigned short* Bp16 = (const unsigned short*)B + (long)b*Bb + (long)h*Bh;
  const int r0 = blockIdx.y*128, c0 = blockIdx.x*128;
  const int wid = tid>>6, lane = tid&63;
  const int wr = wid>>1, wc = wid&1;
  const int lr = lane&15, lg = lane>>4;
  float stabB = 0.f;
  if (EXPB) stabB = decmax(estab[0]);
  float kpart[KSUM?8:1] = {};
  float qs0 = 0.f, qs1 = 0.f;
  f32x4 acc[4][4] = {};

  for (int k0=0; k0<K; k0+=32){
    // ---- stage A tile -> Asm[r][k]
    if constexpr (EXPA){
      #pragma unroll
      for (int it=0; it<2; ++it){
        int idx = tid + it*256;
        int r = idx>>2, kq = (idx&3)*8;
        long grow = (long)bz*R + (r0+r);
        float dg = ediag[grow];
        float st = decmax(estab[grow]);
        u16x8 raw = *reinterpret_cast<const u16x8*>(Ap16 + (long)(r0+r)*lda + (k0+kq));
        float qacc = 0.f;
        #pragma unroll
        for (int i=0;i<8;i++){
          int kk = k0+kq+i;
          float v = (kk < Mvalid) ? ratio*(expf(b2f(raw[i])-dg-st)+eps) : 0.0f;
          Asm[r][kq+i] = f2b(v);
          if (QDIV) qacc = fmaf(v, ksumio[(long)bz*K + kk], qacc);
        }
        if (QDIV){ if (it==0) qs0 += qacc; else qs1 += qacc; }
      }
    } else if constexpr (!A_CM){
      #pragma unroll
      for (int it=0; it<2; ++it){
        int idx = tid + it*256;
        int r = idx>>2, kq = (idx&3)*8;
        u16x8 v = *reinterpret_cast<const u16x8*>(Ap16 + (long)(r0+r)*lda + (k0+kq));
        *reinterpret_cast<u16x8*>(&Asm[r][kq]) = v;
      }
    } else {
      #pragma unroll
      for (int it=0; it<2; ++it){
        int idx = tid + it*256;
        int k = idx>>4, rq = (idx&15)*8;
        u16x8 v = {};
        if (r0+rq < R) v = *reinterpret_cast<const u16x8*>(Ap16 + (long)(k0+k)*lda + (r0+rq));
        #pragma unroll
        for (int i=0;i<8;i++) Asm[rq+i][k] = v[i];
      }
    }
    // ---- stage B tile -> Bsm[c][k]
    if constexpr (EXPB){
      #pragma unroll
      for (int it=0; it<2; ++it){
        int idx = tid + it*256;
        int k = idx>>4, cq = (idx&15)*8;
        float dg = ediag[(long)bz*K + (k0+k)];
        u16x8 raw = {};
        bool inb = (c0+cq < NC);
        if (inb) raw = *reinterpret_cast<const u16x8*>(Bp16 + (long)(k0+k)*ldb + (c0+cq));
        #pragma unroll
        for (int i=0;i<8;i++){
          int c = c0+cq+i;
          float v = (c < Mvalid && inb) ? ratio*(expf(b2f(raw[i])-dg-stabB)+eps) : 0.0f;
          Bsm[cq+i][k] = f2b(v);
          if (KSUM) kpart[i] += v;
        }
      }
    } else if constexpr (B_CM){
      #pragma unroll
      for (int it=0; it<2; ++it){
        int idx = tid + it*256;
        int c = idx>>2, kq = (idx&3)*8;
        u16x8 v = {};
        if (c0+c < NC) v = *reinterpret_cast<const u16x8*>(Bp16 + (long)(c0+c)*ldb + (k0+kq));
        *reinterpret_cast<u16x8*>(&Bsm[c][kq]) = v;
      }
    } else {
      #pragma unroll
      for (int it=0; it<2; ++it){
        int idx = tid + it*256;
        int k = idx>>4, cq = (idx&15)*8;
        u16x8 v = {};
        if (c0+cq < NC) v = *reinterpret_cast<const u16x8*>(Bp16 + (long)(k0+k)*ldb + (c0+cq));
        #pragma unroll
        for (int i=0;i<8;i++) Bsm[cq+i][k] = v[i];
      }
    }
    __syncthreads();
    bf16x8 af[4], bfr[4];
    #pragma unroll
    for (int m=0;m<4;m++) af[m] = *reinterpret_cast<const bf16x8*>(&Asm[wr*64+m*16+lr][lg*8]);
    #pragma unroll
    for (int n=0;n<4;n++) bfr[n] = *reinterpret_cast<const bf16x8*>(&Bsm[wc*64+n*16+lr][lg*8]);
    #pragma unroll
    for (int m=0;m<4;m++)
      #pragma unroll
      for (int n=0;n<4;n++)
        acc[m][n] = __builtin_amdgcn_mfma_f32_16x16x32_bf16(af[m], bfr[n], acc[m][n], 0, 0, 0);
    __syncthreads();
  }

  // ---- fused max epilogues
  if constexpr (MAXM==1){
    float mx = -INFINITY;
    #pragma unroll
    for (int m=0;m<4;m++)
      #pragma unroll
      for (int n=0;n<4;n++)
        #pragma unroll
        for (int e=0;e<4;e++) mx = fmaxf(mx, acc[m][n][e]);
    mx *= alpha;
    mx = wave_max(mx);
    if (lane==0) sred[wid]=mx;
    __syncthreads();
    if (tid==0) atomicMax(maxu, encmax(fmaxf(fmaxf(sred[0],sred[1]),fmaxf(sred[2],sred[3]))));
  }
  if constexpr (MAXM==2){
    #pragma unroll
    for (int m=0;m<4;m++){
      #pragma unroll
      for (int e=0;e<4;e++){
        float mx = acc[m][0][e];
        #pragma unroll
        for (int n=1;n<4;n++) mx = fmaxf(mx, acc[m][n][e]);
        mx *= alpha;
        #pragma unroll
        for (int o=1;o<16;o<<=1) mx = fmaxf(mx, __shfl_xor(mx, o));
        if (lr==0){
          int gr = r0 + wr*64 + m*16 + lg*4 + e;
          atomicMax(maxu + (long)bz*R + gr, encmax(mx));
        }
      }
    }
  }
  // ---- fused kpsum / dinv reductions
  if constexpr (KSUM){
    #pragma unroll
    for (int j=0;j<8;j++) ks_lds[tid>>4][(tid&15)*8+j] = kpart[j];
    __syncthreads();
    if (tid < 128){
      float s = 0.f;
      #pragma unroll
      for (int g=0;g<16;g++) s += ks_lds[g][tid];
      int gc = c0 + tid;
      if (gc < NC) ksumio[(long)bz*NC + gc] = s;
    }
  }
  if constexpr (QDIV){
    qs_lds[tid>>2][tid&3] = qs0;
    qs_lds[64+(tid>>2)][tid&3] = qs1;
    __syncthreads();
    if (tid < 128)
      dinv_lds[tid] = 1.0f/(qs_lds[tid][0]+qs_lds[tid][1]+qs_lds[tid][2]+qs_lds[tid][3]);
    __syncthreads();
  }

  float* Cf = (float*)C;
  unsigned short* Cb16 = (unsigned short*)C;
  const long coff = (long)b*Cb + (long)h*Ch;
  #pragma unroll
  for (int m=0;m<4;m++){
    #pragma unroll
    for (int n=0;n<4;n++){
      #pragma unroll
      for (int e=0;e<4;e++){
        int r = wr*64 + m*16 + lg*4 + e;
        int c = wc*64 + n*16 + lr;
        int gr = r0 + r, gc = c0 + c;
        if (gr < R && gc < NC){
          float v = acc[m][n][e] * alpha;
          if (EPI >= 2) v += bias[gc];
          if (EPI == 2) v = gelu_tanh(v);
          if (rowscale) v *= rowscale[(long)bz*rsn + gr];
          if (QDIV) v *= dinv_lds[r];
          if (EPI == 3) v += res[(long)gr*ldc + gc];
          long o = coff + (long)gr*ldc + gc;
          if (OUT_BF16) Cb16[o] = f2b(v); else Cf[o] = v;
        }
      }
    }
  }
}

// ---------------- diag for K and Q segments + init ROWMAXU/REDU ----------------
__global__ __launch_bounds__(256) void k_diag2(const unsigned short* __restrict__ KQ,
    float* __restrict__ DIAG, unsigned* __restrict__ ROWMAXU, unsigned* __restrict__ REDU,
    int bhn, int rows, int n, int I, int dh, int H, float dn)
{
  int row = blockIdx.x*4 + (threadIdx.x >> 6);
  int lane = threadIdx.x & 63;
  if (row >= 2*bhn) return;
  int seg = row < bhn ? 0 : 1;
  int r = row - seg*bhn;
  int ni = r % n; int bhh = r / n; int h = bhh % H; int b = bhh / H;
  const unsigned short* p = KQ + (long)seg*rows*I + ((long)(b*n + ni))*I + h*dh;
  float s = 0.f;
  for (int i=lane;i<dh;i+=64){ float v=b2f(p[i]); s += v*v; }
  s = wave_sum(s);
  if (lane==0){
    DIAG[row] = 0.5f*dn*dn*s;
    if (seg==0){
      ROWMAXU[r] = 0u;
      if (r==0) REDU[0] = 0u;
    }
  }
}

// ---------------- final mean over s ----------------
__global__ __launch_bounds__(256) void k_mean(const float* __restrict__ X,
    float* __restrict__ out)
{
  int idx = blockIdx.x*256 + threadIdx.x;   // b*128+f
  int f = idx & 127, b = idx >> 7;
  const float* p = X + (long)b*256*128 + f;
  float s = 0.f;
  for (int i=0;i<256;i++) s += p[i*128];
  out[idx] = s*(1.0f/256.0f);
}

// ---------------- host-side stage driver ----------------
struct StageP {
  const float *ln1w,*ln1b,*wob,*ln2w,*ln2b,*f1b,*f2b;
  const unsigned short *wkqvT,*woT,*f1T,*f2T,*projb;
  int n, D, H, dh, I, M, Mp;
};

static void run_stage(const StageP& P, float* X, unsigned short* LNb,
    unsigned short* KQVb, unsigned short* DDk, unsigned short* DDq, unsigned short* CTXT,
    unsigned short* ATTNb, unsigned short* FFHb,
    float* KPSUM, float* DIAG, unsigned* ROWMAXU, unsigned* REDU,
    hipStream_t stream)
{
  const int B = 64;
  const int rows = B*P.n;
  const int bh = B*P.H;
  const int bhn = bh*P.n;
  const float dn = powf((float)P.dh, -0.25f);
  const float ratio = 1.0f/sqrtf((float)P.M);
  const float eps = 1e-4f;

  const unsigned short* Kb = KQVb;                       // K segment first
  const unsigned short* Qb = KQVb + (long)rows*P.I;
  const unsigned short* Vb = KQVb + 2L*rows*P.I;
  const float* DIAGK = DIAG;
  const float* DIAGQ = DIAG + bhn;

  for (int l=0;l<4;l++){
    const float* ln1w = P.ln1w + (long)l*P.D;
    const float* ln1b = P.ln1b + (long)l*P.D;
    const float* wob  = P.wob  + (long)l*P.D;
    const float* ln2w = P.ln2w + (long)l*P.D;
    const float* ln2b = P.ln2b + (long)l*P.D;
    const float* f1b  = P.f1b  + (long)l*4*P.D;
    const float* f2b_ = P.f2b  + (long)l*P.D;
    const unsigned short* wkqvT = P.wkqvT + (long)l*3*P.D*P.I;
    const unsigned short* woT = P.woT + (long)l*P.I*P.D;
    const unsigned short* f1T = P.f1T + (long)l*P.D*4*P.D;
    const unsigned short* f2T = P.f2T + (long)l*4*P.D*P.D;
    const unsigned short* pjb = P.projb + (long)l*P.Mp*P.dh;

    k_ln<<<dim3((rows+3)/4),dim3(256),0,stream>>>(X, ln1w, ln1b, LNb, rows, P.D);
    // fused K,Q,V projection: grid.z selects weight/output segment
    dim3 gq((P.I+127)/128, rows/128, 3);
    k_mgemm<false,true,0,true,false,false,0,false,false><<<gq,dim3(256),0,stream>>>(
        LNb, wkqvT, KQVb, nullptr,nullptr,nullptr, nullptr,nullptr,nullptr,nullptr, 0,0,0,
        1.f, 1, rows, P.I, P.D,
        0,0,(long)P.D,
        (long)P.I*P.D,0,(long)P.D,
        (long)rows*P.I,0,(long)P.I, 0);
    // diag for K and Q + init ROWMAXU/REDU
    k_diag2<<<dim3((2*bhn+3)/4),dim3(256),0,stream>>>(KQVb, DIAG, ROWMAXU, REDU,
        bhn, rows, P.n, P.I, P.dh, P.H, dn);
    // dd_k -> DDk (bf16), fused global max (fp32 acc)
    dim3 gdd((P.Mp+127)/128, P.n/128, bh);
    k_mgemm<false,true,0,true,false,false,1,false,false><<<gdd,dim3(256),0,stream>>>(
        Kb, pjb, DDk, nullptr,nullptr,nullptr, nullptr,nullptr,REDU,nullptr, 0,0,0,
        dn, P.H, P.n, P.Mp, P.dh,
        (long)P.n*P.I, (long)P.dh, (long)P.I,
        0, 0, (long)P.dh,
        (long)P.H*P.n*P.Mp, (long)P.n*P.Mp, (long)P.Mp, 0);
    // CTXT = V^T @ kp with exp fused on B-stage + fused kpsum
    dim3 gctx((P.Mp+127)/128, (P.dh+127)/128, bh);
    k_mgemm<true,false,0,true,false,true,0,true,false><<<gctx,dim3(256),0,stream>>>(
        Vb, DDk, CTXT, nullptr,nullptr,nullptr, DIAGK, REDU, nullptr, KPSUM,
        ratio, eps, P.M,
        1.f, P.H, P.dh, P.Mp, P.n,
        (long)P.n*P.I, (long)P.dh, (long)P.I,
        (long)P.H*P.n*P.Mp, (long)P.n*P.Mp, (long)P.Mp,
        (long)P.H*P.dh*P.Mp, (long)P.dh*P.Mp, (long)P.Mp, 0);
    // dd_q -> DDq (bf16), fused row max (fp32 acc)
    k_mgemm<false,true,0,true,false,false,2,false,false><<<gdd,dim3(256),0,stream>>>(
        Qb, pjb, DDq, nullptr,nullptr,nullptr, nullptr,nullptr,ROWMAXU,nullptr, 0,0,0,
        dn, P.H, P.n, P.Mp, P.dh,
        (long)P.n*P.I, (long)P.dh, (long)P.I,
        0, 0, (long)P.dh,
        (long)P.H*P.n*P.Mp, (long)P.n*P.Mp, (long)P.Mp, 0);
    // out = (qp @ ctx) * dinv, exp fused on A-stage + fused dinv
    dim3 gout((P.dh+127)/128, P.n/128, bh);
    k_mgemm<false,true,0,true,true,false,0,false,true><<<gout,dim3(256),0,stream>>>(
        DDq, CTXT, ATTNb, nullptr,nullptr,nullptr, DIAGQ, ROWMAXU, nullptr, KPSUM,
        ratio, eps, P.M,
        1.f, P.H, P.n, P.dh, P.Mp,
        (long)P.H*P.n*P.Mp, (long)P.n*P.Mp, (long)P.Mp,
        (long)P.H*P.dh*P.Mp, (long)P.dh*P.Mp, (long)P.Mp,
        (long)P.n*P.I, (long)P.dh, (long)P.I, P.n);
    // x = x + attn @ wo + wob
    dim3 gwo((P.D+127)/128, rows/128, 1);
    k_mgemm<false,true,3,false,false,false,0,false,false><<<gwo,dim3(256),0,stream>>>(
        ATTNb, woT, X, wob, X, nullptr, nullptr,nullptr,nullptr,nullptr, 0,0,0,
        1.f, 1, rows, P.D, P.I, 0,0,(long)P.I, 0,0,(long)P.I, 0,0,(long)P.D, 0);
    // ff
    k_ln<<<dim3((rows+3)/4),dim3(256),0,stream>>>(X, ln2w, ln2b, LNb, rows, P.D);
    dim3 gf1((4*P.D+127)/128, rows/128, 1);
    k_mgemm<false,true,2,true,false,false,0,false,false><<<gf1,dim3(256),0,stream>>>(
        LNb, f1T, FFHb, f1b, nullptr, nullptr, nullptr,nullptr,nullptr,nullptr, 0,0,0,
        1.f, 1, rows, 4*P.D, P.D, 0,0,(long)P.D, 0,0,(long)P.D, 0,0,(long)(4*P.D), 0);
    dim3 gf2((P.D+127)/128, rows/128, 1);
    k_mgemm<false,true,3,false,false,false,0,false,false><<<gf2,dim3(256),0,stream>>>(
        FFHb, f2T, X, f2b_, X, nullptr, nullptr,nullptr,nullptr,nullptr, 0,0,0,
        1.f, 1, rows, P.D, 4*P.D, 0,0,(long)(4*P.D), 0,0,(long)(4*P.D), 0,0,(long)P.D, 0);
  }
}

// ---------------- entry ----------------
extern "C" void kernel_launch(void* const* d_in, const int* in_sizes, int n_in,
                              void* d_out, int out_size, void* d_ws, size_t ws_size,
                              hipStream_t stream)
{
  const float* x     = (const float*)d_in[0];
  const float* lin_w = (const float*)d_in[1];
  const float* lin_b = (const float*)d_in[2];

  char* wsb = (char*)d_ws;
  size_t off = 0;
  auto alloc = [&](size_t bytes)->void*{ void* p = wsb + off; off += (bytes + 255) & ~(size_t)255; return p; };
  float* X     = (float*)alloc(8388608);
  float* X2    = (float*)alloc(8388608);
  unsigned short* LNb   = (unsigned short*)alloc(4194304);
  unsigned short* KQVb  = (unsigned short*)alloc(31457280);   // [K][Q][V] bf16
  unsigned short* DDk   = (unsigned short*)alloc(52428800);   // bf16 dd
  unsigned short* DDq   = (unsigned short*)alloc(52428800);
  unsigned short* CTXT  = (unsigned short*)alloc(52428800);
  unsigned short* ATTNb = (unsigned short*)alloc(10485760);
  unsigned short* WKQV1 = (unsigned short*)alloc(3932160);    // [L][3][I][D]
  unsigned short* WO1T  = (unsigned short*)alloc(1310720);
  unsigned short* F11T  = (unsigned short*)alloc(2097152);
  unsigned short* F21T  = (unsigned short*)alloc(2097152);
  unsigned short* WKQV2 = (unsigned short*)alloc(786432);
  unsigned short* WO2T  = (unsigned short*)alloc(262144);
  unsigned short* F12T  = (unsigned short*)alloc(524288);
  unsigned short* F22T  = (unsigned short*)alloc(524288);
  unsigned short* PJ1   = (unsigned short*)alloc(655360);
  unsigned short* PJ2   = (unsigned short*)alloc(147456);
  float* KPSUM = (float*)alloc(819200);
  float* DIAG  = (float*)alloc(524288);
  unsigned* ROWMAXU = (unsigned*)alloc(262144);
  unsigned* REDU = (unsigned*)alloc(256);
  unsigned short* FFHb = DDk;   // FF hidden aliases DDk (dead during FF)
  if (ws_size < off) return;

  // ---- weight conversions: pack K,Q,V contiguously per layer ----
  k_wt<<<dim3(640/32,256/32,4),dim3(256),0,stream>>>((const float*)d_in[6],  WKQV1+0L*640*256, 256, 640, 3L*640*256);
  k_wt<<<dim3(640/32,256/32,4),dim3(256),0,stream>>>((const float*)d_in[5],  WKQV1+1L*640*256, 256, 640, 3L*640*256);
  k_wt<<<dim3(640/32,256/32,4),dim3(256),0,stream>>>((const float*)d_in[7],  WKQV1+2L*640*256, 256, 640, 3L*640*256);
  k_wt<<<dim3(256/32,640/32,4),dim3(256),0,stream>>>((const float*)d_in[8],  WO1T, 640, 256, 640L*256);
  k_wt<<<dim3(1024/32,256/32,4),dim3(256),0,stream>>>((const float*)d_in[12], F11T, 256, 1024, 1024L*256);
  k_wt<<<dim3(256/32,1024/32,4),dim3(256),0,stream>>>((const float*)d_in[14], F21T, 1024, 256, 1024L*256);
  k_wt<<<dim3(256/32,128/32,4),dim3(256),0,stream>>>((const float*)d_in[20], WKQV2+0L*256*128, 128, 256, 3L*256*128);
  k_wt<<<dim3(256/32,128/32,4),dim3(256),0,stream>>>((const float*)d_in[19], WKQV2+1L*256*128, 128, 256, 3L*256*128);
  k_wt<<<dim3(256/32,128/32,4),dim3(256),0,stream>>>((const float*)d_in[21], WKQV2+2L*256*128, 128, 256, 3L*256*128);
  k_wt<<<dim3(128/32,256/32,4),dim3(256),0,stream>>>((const float*)d_in[22], WO2T, 256, 128, 256L*128);
  k_wt<<<dim3(512/32,128/32,4),dim3(256),0,stream>>>((const float*)d_in[26], F12T, 128, 512, 512L*128);
  k_wt<<<dim3(128/32,512/32,4),dim3(256),0,stream>>>((const float*)d_in[28], F22T, 512, 128, 512L*128);
  {
    long t1 = 4L*640*128;
    k_projconv<<<dim3((int)((t1+255)/256)),dim3(256),0,stream>>>((const float*)d_in[16], PJ1, 620, 640, 128, t1);
    long t2 = 4L*288*64;
    k_projconv<<<dim3((int)((t2+255)/256)),dim3(256),0,stream>>>((const float*)d_in[30], PJ2, 266, 288, 64, t2);
  }

  StageP T;
  T.ln1w=(const float*)d_in[3];  T.ln1b=(const float*)d_in[4];
  T.wob=(const float*)d_in[9];
  T.ln2w=(const float*)d_in[10]; T.ln2b=(const float*)d_in[11];
  T.f1b=(const float*)d_in[13];  T.f2b=(const float*)d_in[15];
  T.wkqvT=WKQV1; T.woT=WO1T; T.f1T=F11T; T.f2T=F21T; T.projb=PJ1;
  T.n=128; T.D=256; T.H=5; T.dh=128; T.I=640; T.M=620; T.Mp=640;

  StageP Ms;
  Ms.ln1w=(const float*)d_in[17]; Ms.ln1b=(const float*)d_in[18];
  Ms.wob=(const float*)d_in[23];
  Ms.ln2w=(const float*)d_in[24]; Ms.ln2b=(const float*)d_in[25];
  Ms.f1b=(const float*)d_in[27];  Ms.f2b=(const float*)d_in[29];
  Ms.wkqvT=WKQV2; Ms.woT=WO2T; Ms.f1T=F12T; Ms.f2T=F22T; Ms.projb=PJ2;
  Ms.n=256; Ms.D=128; Ms.H=4; Ms.dh=64; Ms.I=256; Ms.M=266; Ms.Mp=288;

  k_embed<<<dim3(8192),dim3(256),0,stream>>>(x, lin_w, lin_b, X);
  run_stage(T, X, LNb, KQVb, DDk, DDq, CTXT, ATTNb, FFHb,
            KPSUM, DIAG, ROWMAXU, REDU, stream);
  k_transpose_pe<<<dim3(8192),dim3(256),0,stream>>>(X, X2);
  run_stage(Ms, X2, LNb, KQVb, DDk, DDq, CTXT, ATTNb, FFHb,
            KPSUM, DIAG, ROWMAXU, REDU, stream);
  k_mean<<<dim3(32),dim3(256),0,stream>>>(X2, (float*)d_out);
}

// Round 6
// 2839.905 us; speedup vs baseline: 3.5708x; 1.0518x over previous
//
#include <hip/hip_runtime.h>
#include <math.h>

using bf16x8 = __attribute__((ext_vector_type(8))) short;
using f32x4  = __attribute__((ext_vector_type(4))) float;
using u16x8  = __attribute__((ext_vector_type(8))) unsigned short;

__device__ __forceinline__ float b2f(unsigned short u){
  union{float f; unsigned int i;} x; x.i = ((unsigned int)u)<<16; return x.f;
}
__device__ __forceinline__ unsigned short f2b(float f){
  union{float f; unsigned int i;} x; x.f = f;
  unsigned int r = x.i + 0x7fffu + ((x.i>>16)&1u);
  return (unsigned short)(r>>16);
}
__device__ __forceinline__ float gelu_tanh(float x){
  float x3 = x*x*x;
  return 0.5f*x*(1.0f + tanhf(0.79788456080286535588f*(x + 0.044715f*x3)));
}
__device__ __forceinline__ float wave_sum(float v){
  #pragma unroll
  for (int o=32;o>0;o>>=1) v += __shfl_down(v,o);
  return v;
}
__device__ __forceinline__ float wave_max(float v){
  #pragma unroll
  for (int o=32;o>0;o>>=1) v = fmaxf(v, __shfl_down(v,o));
  return v;
}
// monotone float<->uint encoding for atomic max (init 0 < any encoded real value)
__device__ __forceinline__ unsigned encmax(float f){
  union{float f; unsigned u;} x; x.f = f;
  return (x.u & 0x80000000u) ? ~x.u : (x.u | 0x80000000u);
}
__device__ __forceinline__ float decmax(unsigned e){
  union{unsigned u; float f;} x;
  x.u = (e & 0x80000000u) ? (e & 0x7fffffffu) : ~e;
  return x.f;
}

// ---------------- embed: per-file linear + transpose + PE(F,S) ----------------
__global__ __launch_bounds__(256) void k_embed(const float* __restrict__ x,
    const float* __restrict__ lw, const float* __restrict__ lb,
    float* __restrict__ X)
{
  int idx = blockIdx.x*256 + threadIdx.x;      // (b*128+f)*256+s
  int s = idx & 255;
  int f = (idx >> 8) & 127;
  int b = idx >> 15;
  const float* xr = x + ((long)(b*256 + s))*2048 + f*16;
  const float* wr = lw + f*16;
  float acc = lb[f];
  #pragma unroll
  for (int c=0;c<16;c++) acc = fmaf(xr[c], wr[c], acc);
  int i = s >> 1;
  float dv = expf((float)(2*i) * (-9.210340371976184f/256.0f));
  float ang = (float)f * dv;
  acc += (s & 1) ? cosf(ang) : sinf(ang);
  X[idx] = acc;
}

// ---------------- transpose [B,128,256]->[B,256,128] + PE(S,F) ----------------
__global__ __launch_bounds__(256) void k_transpose_pe(const float* __restrict__ X,
    float* __restrict__ Y)
{
  int idx = blockIdx.x*256 + threadIdx.x;      // (b*256+s)*128+f
  int f = idx & 127;
  int s = (idx >> 7) & 255;
  int b = idx >> 15;
  int i = f >> 1;
  float dv = expf((float)(2*i) * (-9.210340371976184f/128.0f));
  float ang = (float)s * dv;
  float pe = (f & 1) ? cosf(ang) : sinf(ang);
  Y[idx] = X[((long)(b*128 + f))*256 + s] + pe;
}

// ---------------- merged weight transpose-convert ----------------
struct WTJobs {
  const float* src[12];
  unsigned short* dst[12];
  int K[12]; int N[12];
  long lstr[12];
};
__global__ __launch_bounds__(256) void k_wtall(WTJobs jt)
{
  __shared__ float t[32][33];
  int j = blockIdx.y;
  int K = jt.K[j], N = jt.N[j];
  int nx = N >> 5, ny = K >> 5;
  if ((int)blockIdx.x >= nx*ny) return;
  int nb = ((int)blockIdx.x % nx)*32, kb = ((int)blockIdx.x / nx)*32;
  int l = blockIdx.z;
  const float* Wp = jt.src[j] + (long)l*K*N;
  unsigned short* Tp = jt.dst[j] + (long)l*jt.lstr[j];
  int tx = threadIdx.x & 31, ty = threadIdx.x >> 5;
  #pragma unroll
  for (int i=0;i<4;i++) t[ty+i*8][tx] = Wp[(long)(kb+ty+i*8)*N + nb+tx];
  __syncthreads();
  #pragma unroll
  for (int i=0;i<4;i++) Tp[(long)(nb+ty+i*8)*K + kb+tx] = f2b(t[tx][ty+i*8]);
}

// ---------------- proj convert + pad ----------------
__global__ __launch_bounds__(256) void k_projconv(const float* __restrict__ proj,
    unsigned short* __restrict__ pb, int M, int Mp, int dh, long total)
{
  long idx = (long)blockIdx.x*256 + threadIdx.x;
  if (idx >= total) return;
  int c = (int)(idx % dh);
  long t = idx / dh;
  int m = (int)(t % Mp);
  int l = (int)(t / Mp);
  pb[idx] = (m < M) ? f2b(proj[((long)l*M + m)*dh + c]) : (unsigned short)0;
}

// ---------------- generic MFMA GEMM ----------------
// C[R,NC] = alpha * A*B (+bias)(+gelu)(+res). K multiple of 32.
// LND>0: A is fp32 X [R][LND]; block computes LayerNorm(lnw,lnb) of its 128 rows
//        into LDS, which serves as the A operand (K == LND).
// EXPB: B is bf16 DD (row-major [K][ldb]); staged as ratio*(exp(b-diag[k]-stab)+eps), 0 for c>=Mvalid
// MAXM==1: global atomic max of alpha*acc into maxu[0]
// KSUM (with EXPB): per-column sums of staged B -> ksumio[bz*NC + c]
template<bool A_CM, bool B_CM, int EPI, bool OUT_BF16, bool EXPB, int MAXM, bool KSUM, int LND>
__global__ __launch_bounds__(256) void k_mgemm(
    const void* __restrict__ A, const void* __restrict__ B, void* __restrict__ C,
    const float* __restrict__ bias, const float* __restrict__ res,
    const float* __restrict__ lnw, const float* __restrict__ lnb,
    const float* __restrict__ ediag, const unsigned* __restrict__ estab,
    unsigned* __restrict__ maxu, float* __restrict__ ksumio,
    float ratio, float eps, int Mvalid,
    float alpha, int H, int R, int NC, int K,
    long Ab, long Ah, long lda,
    long Bb, long Bh, long ldb,
    long Cb, long Ch, long ldc)
{
  __shared__ unsigned short Asm[LND?1:128][LND?1:40];
  __shared__ unsigned short LNbuf[LND?128:1][LND?(LND+8):1];
  __shared__ unsigned short Bsm[128][40];
  __shared__ float sred[4];
  __shared__ float ks_lds[KSUM?16:1][KSUM?132:1];
  const int tid = threadIdx.x;
  const int bz = blockIdx.z;
  const int b = bz / H, h = bz - b*H;
  const unsigned short* Ap16 = (const unsigned short*)A + (long)b*Ab + (long)h*Ah;
  const unsigned short* Bp16 = (const unsigned short*)B + (long)b*Bb + (long)h*Bh;
  const int r0 = blockIdx.y*128, c0 = blockIdx.x*128;
  const int wid = tid>>6, lane = tid&63;
  const int wr = wid>>1, wc = wid&1;
  const int lr = lane&15, lg = lane>>4;
  float stabB = 0.f;
  if (EXPB) stabB = decmax(estab[0]);
  float kpart[KSUM?8:1] = {};
  f32x4 acc[4][4] = {};

  if constexpr (LND>0){
    // fused LayerNorm prologue: wave per row, coalesced
    const float* Xp = (const float*)A;
    for (int rr = wid*32; rr < wid*32+32; ++rr){
      const float* xr = Xp + (long)(r0+rr)*LND;
      float s=0.f, sq=0.f;
      #pragma unroll
      for (int i=0;i<LND/64;i++){ float v = xr[lane + i*64]; s += v; sq += v*v; }
      s = wave_sum(s); sq = wave_sum(sq);
      s = __shfl(s,0); sq = __shfl(sq,0);
      float mu = s*(1.0f/(float)LND);
      float inv = rsqrtf(sq*(1.0f/(float)LND) - mu*mu + 1e-5f);
      #pragma unroll
      for (int i=0;i<LND/64;i++){
        int cc = lane + i*64;
        LNbuf[rr][cc] = f2b((xr[cc]-mu)*inv*lnw[cc] + lnb[cc]);
      }
    }
    __syncthreads();
  }

  for (int k0=0; k0<K; k0+=32){
    // ---- stage A tile -> Asm[r][k] (skipped when LND: A lives in LNbuf)
    if constexpr (LND==0){
      if constexpr (!A_CM){
        #pragma unroll
        for (int it=0; it<2; ++it){
          int idx = tid + it*256;
          int r = idx>>2, kq = (idx&3)*8;
          u16x8 v = *reinterpret_cast<const u16x8*>(Ap16 + (long)(r0+r)*lda + (k0+kq));
          *reinterpret_cast<u16x8*>(&Asm[r][kq]) = v;
        }
      } else {
        #pragma unroll
        for (int it=0; it<2; ++it){
          int idx = tid + it*256;
          int k = idx>>4, rq = (idx&15)*8;
          u16x8 v = {};
          if (r0+rq < R) v = *reinterpret_cast<const u16x8*>(Ap16 + (long)(k0+k)*lda + (r0+rq));
          #pragma unroll
          for (int i=0;i<8;i++) Asm[rq+i][k] = v[i];
        }
      }
    }
    // ---- stage B tile -> Bsm[c][k]
    if constexpr (EXPB){
      #pragma unroll
      for (int it=0; it<2; ++it){
        int idx = tid + it*256;
        int k = idx>>4, cq = (idx&15)*8;
        float dg = ediag[(long)bz*K + (k0+k)];
        u16x8 raw = {};
        bool inb = (c0+cq < NC);
        if (inb) raw = *reinterpret_cast<const u16x8*>(Bp16 + (long)(k0+k)*ldb + (c0+cq));
        #pragma unroll
        for (int i=0;i<8;i++){
          int c = c0+cq+i;
          float v = (c < Mvalid && inb) ? ratio*(expf(b2f(raw[i])-dg-stabB)+eps) : 0.0f;
          Bsm[cq+i][k] = f2b(v);
          if (KSUM) kpart[i] += v;
        }
      }
    } else if constexpr (B_CM){
      #pragma unroll
      for (int it=0; it<2; ++it){
        int idx = tid + it*256;
        int c = idx>>2, kq = (idx&3)*8;
        u16x8 v = {};
        if (c0+c < NC) v = *reinterpret_cast<const u16x8*>(Bp16 + (long)(c0+c)*ldb + (k0+kq));
        *reinterpret_cast<u16x8*>(&Bsm[c][kq]) = v;
      }
    } else {
      #pragma unroll
      for (int it=0; it<2; ++it){
        int idx = tid + it*256;
        int k = idx>>4, cq = (idx&15)*8;
        u16x8 v = {};
        if (c0+cq < NC) v = *reinterpret_cast<const u16x8*>(Bp16 + (long)(k0+k)*ldb + (c0+cq));
        #pragma unroll
        for (int i=0;i<8;i++) Bsm[cq+i][k] = v[i];
      }
    }
    __syncthreads();
    bf16x8 af[4], bfr[4];
    #pragma unroll
    for (int m=0;m<4;m++){
      if constexpr (LND>0)
        af[m] = *reinterpret_cast<const bf16x8*>(&LNbuf[wr*64+m*16+lr][k0+lg*8]);
      else
        af[m] = *reinterpret_cast<const bf16x8*>(&Asm[wr*64+m*16+lr][lg*8]);
    }
    #pragma unroll
    for (int n=0;n<4;n++) bfr[n] = *reinterpret_cast<const bf16x8*>(&Bsm[wc*64+n*16+lr][lg*8]);
    #pragma unroll
    for (int m=0;m<4;m++)
      #pragma unroll
      for (int n=0;n<4;n++)
        acc[m][n] = __builtin_amdgcn_mfma_f32_16x16x32_bf16(af[m], bfr[n], acc[m][n], 0, 0, 0);
    __syncthreads();
  }

  // ---- fused global max epilogue
  if constexpr (MAXM==1){
    float mx = -INFINITY;
    #pragma unroll
    for (int m=0;m<4;m++)
      #pragma unroll
      for (int n=0;n<4;n++)
        #pragma unroll
        for (int e=0;e<4;e++) mx = fmaxf(mx, acc[m][n][e]);
    mx *= alpha;
    mx = wave_max(mx);
    if (lane==0) sred[wid]=mx;
    __syncthreads();
    if (tid==0) atomicMax(maxu, encmax(fmaxf(fmaxf(sred[0],sred[1]),fmaxf(sred[2],sred[3]))));
  }
  // ---- fused kpsum reduction
  if constexpr (KSUM){
    #pragma unroll
    for (int j=0;j<8;j++) ks_lds[tid>>4][(tid&15)*8+j] = kpart[j];
    __syncthreads();
    if (tid < 128){
      float s = 0.f;
      #pragma unroll
      for (int g=0;g<16;g++) s += ks_lds[g][tid];
      int gc = c0 + tid;
      if (gc < NC) ksumio[(long)bz*NC + gc] = s;
    }
  }

  float* Cf = (float*)C;
  unsigned short* Cb16 = (unsigned short*)C;
  const long coff = (long)b*Cb + (long)h*Ch;
  #pragma unroll
  for (int m=0;m<4;m++){
    #pragma unroll
    for (int n=0;n<4;n++){
      #pragma unroll
      for (int e=0;e<4;e++){
        int r = wr*64 + m*16 + lg*4 + e;
        int c = wc*64 + n*16 + lr;
        int gr = r0 + r, gc = c0 + c;
        if (gr < R && gc < NC){
          float v = acc[m][n][e] * alpha;
          if (EPI >= 2) v += bias[gc];
          if (EPI == 2) v = gelu_tanh(v);
          if (EPI == 3) v += res[(long)gr*ldc + gc];
          long o = coff + (long)gr*ldc + gc;
          if (OUT_BF16) Cb16[o] = f2b(v); else Cf[o] = v;
        }
      }
    }
  }
}

// ---------------- fused Q-side: dd_q + rowmax + exp + (qp @ CTXT) * dinv ----------------
// Per block: 64 query rows of one (b,h). Two passes over m-chunks of 64:
// pass 1 computes dd (MFMA) for the row max; pass 2 recomputes dd, exps into LDS qp,
// accumulates dinv denominator, and MFMAs qp against the CTXT chunk.
template<int DH, int MP, int MM, int NCH, int NOUT>
__global__ __launch_bounds__(256) void k_qout(
    const unsigned short* __restrict__ Qb,   // [rows][I], head offset h*DH
    const unsigned short* __restrict__ proj, // [MP][DH] bf16 (pad rows zero)
    const unsigned short* __restrict__ CTXT, // per bh: [DH][MP]
    const float* __restrict__ diagq,         // [bh*n]
    const float* __restrict__ ksum,          // [bh*MP]
    unsigned short* __restrict__ out,        // [rows][I]
    float dn, float ratio, float eps,
    int H, int n, int I)
{
  constexpr int QP = DH + 8;
  constexpr int BSZ = (64*QP > DH*72) ? 64*QP : DH*72;
  __shared__ unsigned short Qs[64][QP];
  __shared__ unsigned short qp[64][72];
  __shared__ unsigned short Bs[BSZ];
  __shared__ float diag_lds[64], rmax_lds[64], qs_lds[64], dinv_lds[64];
  const int tid = threadIdx.x;
  const int bz = blockIdx.z;
  const int b = bz / H, h = bz - b*H;
  const int ni0 = blockIdx.y*64;
  const int wid = tid>>6, lane = tid&63;
  const int wr = wid>>1, wc = wid&1;
  const int lr = lane&15, lg = lane>>4;
  const long ctxoff = (long)bz*DH*MP;

  // load Q tile [64][DH] and diag
  const unsigned short* Qp = Qb + ((long)(b*n + ni0))*I + h*DH;
  #pragma unroll
  for (int it=0; it<DH/32; ++it){
    int idx = tid + it*256;
    int r = idx/(DH/8), seg = idx%(DH/8);
    *reinterpret_cast<u16x8*>(&Qs[r][seg*8]) =
        *reinterpret_cast<const u16x8*>(Qp + (long)r*I + seg*8);
  }
  if (tid < 64) diag_lds[tid] = diagq[(long)bz*n + ni0 + tid];
  __syncthreads();

  // ---- pass 1: row max over all chunks
  float rmax[2][4];
  #pragma unroll
  for (int m=0;m<2;m++)
    #pragma unroll
    for (int e=0;e<4;e++) rmax[m][e] = -INFINITY;
  for (int mc=0; mc<NCH; ++mc){
    #pragma unroll
    for (int it=0; it<DH/32; ++it){
      int idx = tid + it*256;
      int c = idx/(DH/8), seg = idx%(DH/8);
      int mg = mc*64 + c;
      u16x8 v = {};
      if (mg < MP) v = *reinterpret_cast<const u16x8*>(proj + (long)mg*DH + seg*8);
      *reinterpret_cast<u16x8*>(&Bs[c*QP + seg*8]) = v;
    }
    __syncthreads();
    f32x4 dacc[2][2] = {};
    #pragma unroll
    for (int ks=0; ks<DH; ks+=32){
      bf16x8 af[2], bf_[2];
      #pragma unroll
      for (int m=0;m<2;m++) af[m] = *reinterpret_cast<const bf16x8*>(&Qs[wr*32+m*16+lr][ks+lg*8]);
      #pragma unroll
      for (int nn=0;nn<2;nn++) bf_[nn] = *reinterpret_cast<const bf16x8*>(&Bs[(wc*32+nn*16+lr)*QP + ks + lg*8]);
      #pragma unroll
      for (int m=0;m<2;m++)
        #pragma unroll
        for (int nn=0;nn<2;nn++)
          dacc[m][nn] = __builtin_amdgcn_mfma_f32_16x16x32_bf16(af[m], bf_[nn], dacc[m][nn], 0, 0, 0);
    }
    #pragma unroll
    for (int m=0;m<2;m++)
      #pragma unroll
      for (int nn=0;nn<2;nn++)
        #pragma unroll
        for (int e=0;e<4;e++) rmax[m][e] = fmaxf(rmax[m][e], dacc[m][nn][e]*dn);
    __syncthreads();
  }
  // reduce rowmax over the 16 lr lanes, then across the two wc waves
  #pragma unroll
  for (int m=0;m<2;m++)
    #pragma unroll
    for (int e=0;e<4;e++){
      #pragma unroll
      for (int o=1;o<16;o<<=1) rmax[m][e] = fmaxf(rmax[m][e], __shfl_xor(rmax[m][e], o));
    }
  if (wc==0 && lr==0){
    #pragma unroll
    for (int m=0;m<2;m++)
      #pragma unroll
      for (int e=0;e<4;e++) rmax_lds[wr*32+m*16+lg*4+e] = rmax[m][e];
  }
  __syncthreads();
  if (wc==1 && lr==0){
    #pragma unroll
    for (int m=0;m<2;m++)
      #pragma unroll
      for (int e=0;e<4;e++){
        int r = wr*32+m*16+lg*4+e;
        rmax_lds[r] = fmaxf(rmax_lds[r], rmax[m][e]);
      }
  }
  __syncthreads();

  // ---- pass 2: recompute dd, exp -> qp, accumulate dinv + out
  float qs[2][4] = {};
  f32x4 oacc[2][NOUT] = {};
  for (int mc=0; mc<NCH; ++mc){
    #pragma unroll
    for (int it=0; it<DH/32; ++it){
      int idx = tid + it*256;
      int c = idx/(DH/8), seg = idx%(DH/8);
      int mg = mc*64 + c;
      u16x8 v = {};
      if (mg < MP) v = *reinterpret_cast<const u16x8*>(proj + (long)mg*DH + seg*8);
      *reinterpret_cast<u16x8*>(&Bs[c*QP + seg*8]) = v;
    }
    __syncthreads();
    f32x4 dacc[2][2] = {};
    #pragma unroll
    for (int ks=0; ks<DH; ks+=32){
      bf16x8 af[2], bf_[2];
      #pragma unroll
      for (int m=0;m<2;m++) af[m] = *reinterpret_cast<const bf16x8*>(&Qs[wr*32+m*16+lr][ks+lg*8]);
      #pragma unroll
      for (int nn=0;nn<2;nn++) bf_[nn] = *reinterpret_cast<const bf16x8*>(&Bs[(wc*32+nn*16+lr)*QP + ks + lg*8]);
      #pragma unroll
      for (int m=0;m<2;m++)
        #pragma unroll
        for (int nn=0;nn<2;nn++)
          dacc[m][nn] = __builtin_amdgcn_mfma_f32_16x16x32_bf16(af[m], bf_[nn], dacc[m][nn], 0, 0, 0);
    }
    // exp -> qp LDS (+ dinv partials)
    #pragma unroll
    for (int m=0;m<2;m++)
      #pragma unroll
      for (int nn=0;nn<2;nn++)
        #pragma unroll
        for (int e=0;e<4;e++){
          int row = wr*32+m*16+lg*4+e;
          int lc = wc*32+nn*16+lr;
          int col = mc*64+lc;
          float v = 0.f;
          if (col < MM){
            v = ratio*(expf(dacc[m][nn][e]*dn - diag_lds[row] - rmax_lds[row]) + eps);
            qs[m][e] = fmaf(v, ksum[(long)bz*MP + col], qs[m][e]);
          }
          qp[row][lc] = f2b(v);
        }
    __syncthreads();   // dd reads of Bs done; qp written
    // stage CTXT chunk: Bs[c*72 + kl], c<DH, kl<64
    #pragma unroll
    for (int it=0; it<DH/32; ++it){
      int idx = tid + it*256;
      int c = idx>>3, kseg = idx&7;
      int kg = mc*64 + kseg*8;
      u16x8 v = {};
      if (kg < MP) v = *reinterpret_cast<const u16x8*>(CTXT + ctxoff + (long)c*MP + kg);
      *reinterpret_cast<u16x8*>(&Bs[c*72 + kseg*8]) = v;
    }
    __syncthreads();
    // out MFMA over this chunk (K=64)
    #pragma unroll
    for (int ks=0; ks<64; ks+=32){
      bf16x8 af[2], bf_[NOUT];
      #pragma unroll
      for (int m=0;m<2;m++) af[m] = *reinterpret_cast<const bf16x8*>(&qp[wr*32+m*16+lr][ks+lg*8]);
      #pragma unroll
      for (int nn=0;nn<NOUT;nn++) bf_[nn] = *reinterpret_cast<const bf16x8*>(&Bs[(wc*(NOUT*16)+nn*16+lr)*72 + ks + lg*8]);
      #pragma unroll
      for (int m=0;m<2;m++)
        #pragma unroll
        for (int nn=0;nn<NOUT;nn++)
          oacc[m][nn] = __builtin_amdgcn_mfma_f32_16x16x32_bf16(af[m], bf_[nn], oacc[m][nn], 0, 0, 0);
    }
    __syncthreads();   // before next chunk overwrites qp/Bs
  }

  // ---- dinv: reduce qs over lr lanes, then across wc waves
  #pragma unroll
  for (int m=0;m<2;m++)
    #pragma unroll
    for (int e=0;e<4;e++){
      #pragma unroll
      for (int o=1;o<16;o<<=1) qs[m][e] += __shfl_xor(qs[m][e], o);
    }
  if (wc==0 && lr==0){
    #pragma unroll
    for (int m=0;m<2;m++)
      #pragma unroll
      for (int e=0;e<4;e++) qs_lds[wr*32+m*16+lg*4+e] = qs[m][e];
  }
  __syncthreads();
  if (wc==1 && lr==0){
    #pragma unroll
    for (int m=0;m<2;m++)
      #pragma unroll
      for (int e=0;e<4;e++) qs_lds[wr*32+m*16+lg*4+e] += qs[m][e];
  }
  __syncthreads();
  if (tid < 64) dinv_lds[tid] = 1.0f/qs_lds[tid];
  __syncthreads();

  unsigned short* Op = out + ((long)(b*n + ni0))*I + h*DH;
  #pragma unroll
  for (int m=0;m<2;m++)
    #pragma unroll
    for (int nn=0;nn<NOUT;nn++)
      #pragma unroll
      for (int e=0;e<4;e++){
        int row = wr*32+m*16+lg*4+e;
        int c = wc*(NOUT*16)+nn*16+lr;
        Op[(long)row*I + c] = f2b(oacc[m][nn][e]*dinv_lds[row]);
      }
}

// ---------------- diag for K and Q segments + init REDU ----------------
__global__ __launch_bounds__(256) void k_diag2(const unsigned short* __restrict__ KQ,
    float* __restrict__ DIAG, unsigned* __restrict__ REDU,
    int bhn, int rows, int n, int I, int dh, int H, float dn)
{
  int row = blockIdx.x*4 + (threadIdx.x >> 6);
  int lane = threadIdx.x & 63;
  if (row >= 2*bhn) return;
  int seg = row < bhn ? 0 : 1;
  int r = row - seg*bhn;
  int ni = r % n; int bhh = r / n; int h = bhh % H; int b = bhh / H;
  const unsigned short* p = KQ + (long)seg*rows*I + ((long)(b*n + ni))*I + h*dh;
  float s = 0.f;
  for (int i=lane;i<dh;i+=64){ float v=b2f(p[i]); s += v*v; }
  s = wave_sum(s);
  if (lane==0){
    DIAG[row] = 0.5f*dn*dn*s;
    if (seg==0 && r==0) REDU[0] = 0u;
  }
}

// ---------------- final mean over s ----------------
__global__ __launch_bounds__(256) void k_mean(const float* __restrict__ X,
    float* __restrict__ out)
{
  int idx = blockIdx.x*256 + threadIdx.x;   // b*128+f
  int f = idx & 127, b = idx >> 7;
  const float* p = X + (long)b*256*128 + f;
  float s = 0.f;
  for (int i=0;i<256;i++) s += p[i*128];
  out[idx] = s*(1.0f/256.0f);
}

// ---------------- host-side stage driver ----------------
struct StageP {
  const float *ln1w,*ln1b,*wob,*ln2w,*ln2b,*f1b,*f2b;
  const unsigned short *wkqvT,*woT,*f1T,*f2T,*projb;
  int n, D, H, dh, I, M, Mp;
};

template<int DCON, int DH, int MP, int MM, int NCH, int NOUT>
static void run_stage(const StageP& P, float* X,
    unsigned short* KQVb, unsigned short* DDk, unsigned short* CTXT,
    unsigned short* ATTNb, unsigned short* FFHb,
    float* KPSUM, float* DIAG, unsigned* REDU,
    hipStream_t stream)
{
  const int B = 64;
  const int rows = B*P.n;
  const int bh = B*P.H;
  const int bhn = bh*P.n;
  const float dn = powf((float)P.dh, -0.25f);
  const float ratio = 1.0f/sqrtf((float)P.M);
  const float eps = 1e-4f;

  const unsigned short* Kb = KQVb;
  const unsigned short* Qb = KQVb + (long)rows*P.I;
  const unsigned short* Vb = KQVb + 2L*rows*P.I;
  const float* DIAGK = DIAG;
  const float* DIAGQ = DIAG + bhn;

  for (int l=0;l<4;l++){
    const float* ln1w = P.ln1w + (long)l*P.D;
    const float* ln1b = P.ln1b + (long)l*P.D;
    const float* wob  = P.wob  + (long)l*P.D;
    const float* ln2w = P.ln2w + (long)l*P.D;
    const float* ln2b = P.ln2b + (long)l*P.D;
    const float* f1b  = P.f1b  + (long)l*4*P.D;
    const float* f2b_ = P.f2b  + (long)l*P.D;
    const unsigned short* wkqvT = P.wkqvT + (long)l*3*P.D*P.I;
    const unsigned short* woT = P.woT + (long)l*P.I*P.D;
    const unsigned short* f1T = P.f1T + (long)l*P.D*4*P.D;
    const unsigned short* f2T = P.f2T + (long)l*4*P.D*P.D;
    const unsigned short* pjb = P.projb + (long)l*P.Mp*P.dh;

    // fused LN1 + K,Q,V projection (z = segment)
    dim3 gq(P.I/128, rows/128, 3);
    k_mgemm<false,true,0,true,false,0,false,DCON><<<gq,dim3(256),0,stream>>>(
        X, wkqvT, KQVb, nullptr,nullptr, ln1w, ln1b, nullptr,nullptr,nullptr,nullptr,
        0,0,0, 1.f, 1, rows, P.I, P.D,
        0,0,(long)P.D,
        (long)P.I*P.D,0,(long)P.D,
        (long)rows*P.I,0,(long)P.I);
    // diag for K and Q + REDU init
    k_diag2<<<dim3((2*bhn+3)/4),dim3(256),0,stream>>>(KQVb, DIAG, REDU,
        bhn, rows, P.n, P.I, P.dh, P.H, dn);
    // dd_k -> DDk (bf16), fused global max
    dim3 gdd((P.Mp+127)/128, P.n/128, bh);
    k_mgemm<false,true,0,true,false,1,false,0><<<gdd,dim3(256),0,stream>>>(
        Kb, pjb, DDk, nullptr,nullptr,nullptr,nullptr, nullptr,nullptr, REDU, nullptr,
        0,0,0, dn, P.H, P.n, P.Mp, P.dh,
        (long)P.n*P.I, (long)P.dh, (long)P.I,
        0, 0, (long)P.dh,
        (long)P.H*P.n*P.Mp, (long)P.n*P.Mp, (long)P.Mp);
    // CTXT = V^T @ kp with exp fused on B-stage + fused kpsum
    dim3 gctx((P.Mp+127)/128, (P.dh+127)/128, bh);
    k_mgemm<true,false,0,true,true,0,true,0><<<gctx,dim3(256),0,stream>>>(
        Vb, DDk, CTXT, nullptr,nullptr,nullptr,nullptr, DIAGK, REDU, nullptr, KPSUM,
        ratio, eps, P.M,
        1.f, P.H, P.dh, P.Mp, P.n,
        (long)P.n*P.I, (long)P.dh, (long)P.I,
        (long)P.H*P.n*P.Mp, (long)P.n*P.Mp, (long)P.Mp,
        (long)P.H*P.dh*P.Mp, (long)P.dh*P.Mp, (long)P.Mp);
    // fused Q side: dd_q + rowmax + exp + (qp@ctx)*dinv -> ATTNb
    dim3 gqo(1, P.n/64, bh);
    k_qout<DH,MP,MM,NCH,NOUT><<<gqo,dim3(256),0,stream>>>(
        Qb, pjb, CTXT, DIAGQ, KPSUM, ATTNb, dn, ratio, eps, P.H, P.n, P.I);
    // x = x + attn @ wo + wob
    dim3 gwo(P.D/128, rows/128, 1);
    k_mgemm<false,true,3,false,false,0,false,0><<<gwo,dim3(256),0,stream>>>(
        ATTNb, woT, X, wob, X, nullptr,nullptr, nullptr,nullptr,nullptr,nullptr,
        0,0,0, 1.f, 1, rows, P.D, P.I, 0,0,(long)P.I, 0,0,(long)P.I, 0,0,(long)P.D);
    // fused LN2 + FF1 (gelu)
    dim3 gf1(4*P.D/128, rows/128, 1);
    k_mgemm<false,true,2,true,false,0,false,DCON><<<gf1,dim3(256),0,stream>>>(
        X, f1T, FFHb, f1b, nullptr, ln2w, ln2b, nullptr,nullptr,nullptr,nullptr,
        0,0,0, 1.f, 1, rows, 4*P.D, P.D, 0,0,(long)P.D, 0,0,(long)P.D, 0,0,(long)(4*P.D));
    // FF2 + residual
    dim3 gf2(P.D/128, rows/128, 1);
    k_mgemm<false,true,3,false,false,0,false,0><<<gf2,dim3(256),0,stream>>>(
        FFHb, f2T, X, f2b_, X, nullptr,nullptr, nullptr,nullptr,nullptr,nullptr,
        0,0,0, 1.f, 1, rows, P.D, 4*P.D, 0,0,(long)(4*P.D), 0,0,(long)(4*P.D), 0,0,(long)P.D);
  }
}

// ---------------- entry ----------------
extern "C" void kernel_launch(void* const* d_in, const int* in_sizes, int n_in,
                              void* d_out, int out_size, void* d_ws, size_t ws_size,
                              hipStream_t stream)
{
  const float* x     = (const float*)d_in[0];
  const float* lin_w = (const float*)d_in[1];
  const float* lin_b = (const float*)d_in[2];

  char* wsb = (char*)d_ws;
  size_t off = 0;
  auto alloc = [&](size_t bytes)->void*{ void* p = wsb + off; off += (bytes + 255) & ~(size_t)255; return p; };
  float* X     = (float*)alloc(8388608);
  float* X2    = (float*)alloc(8388608);
  unsigned short* KQVb  = (unsigned short*)alloc(31457280);   // [K][Q][V] bf16
  unsigned short* DDk   = (unsigned short*)alloc(52428800);   // bf16 dd_k (aliased as FF hidden)
  unsigned short* CTXT  = (unsigned short*)alloc(52428800);
  unsigned short* ATTNb = (unsigned short*)alloc(10485760);
  unsigned short* WKQV1 = (unsigned short*)alloc(3932160);    // [L][3][I][D]
  unsigned short* WO1T  = (unsigned short*)alloc(1310720);
  unsigned short* F11T  = (unsigned short*)alloc(2097152);
  unsigned short* F21T  = (unsigned short*)alloc(2097152);
  unsigned short* WKQV2 = (unsigned short*)alloc(786432);
  unsigned short* WO2T  = (unsigned short*)alloc(262144);
  unsigned short* F12T  = (unsigned short*)alloc(524288);
  unsigned short* F22T  = (unsigned short*)alloc(524288);
  unsigned short* PJ1   = (unsigned short*)alloc(655360);
  unsigned short* PJ2   = (unsigned short*)alloc(147456);
  float* KPSUM = (float*)alloc(819200);
  float* DIAG  = (float*)alloc(524288);
  unsigned* REDU = (unsigned*)alloc(256);
  unsigned short* FFHb = DDk;   // FF hidden aliases DDk (dead during FF)
  if (ws_size < off) return;

  // ---- merged weight conversions ----
  WTJobs jt;
  jt.src[0]=(const float*)d_in[6];  jt.dst[0]=WKQV1+0L*640*256;  jt.K[0]=256; jt.N[0]=640;  jt.lstr[0]=3L*640*256;
  jt.src[1]=(const float*)d_in[5];  jt.dst[1]=WKQV1+1L*640*256;  jt.K[1]=256; jt.N[1]=640;  jt.lstr[1]=3L*640*256;
  jt.src[2]=(const float*)d_in[7];  jt.dst[2]=WKQV1+2L*640*256;  jt.K[2]=256; jt.N[2]=640;  jt.lstr[2]=3L*640*256;
  jt.src[3]=(const float*)d_in[8];  jt.dst[3]=WO1T;              jt.K[3]=640; jt.N[3]=256;  jt.lstr[3]=640L*256;
  jt.src[4]=(const float*)d_in[12]; jt.dst[4]=F11T;              jt.K[4]=256; jt.N[4]=1024; jt.lstr[4]=1024L*256;
  jt.src[5]=(const float*)d_in[14]; jt.dst[5]=F21T;              jt.K[5]=1024;jt.N[5]=256;  jt.lstr[5]=1024L*256;
  jt.src[6]=(const float*)d_in[20]; jt.dst[6]=WKQV2+0L*256*128;  jt.K[6]=128; jt.N[6]=256;  jt.lstr[6]=3L*256*128;
  jt.src[7]=(const float*)d_in[19]; jt.dst[7]=WKQV2+1L*256*128;  jt.K[7]=128; jt.N[7]=256;  jt.lstr[7]=3L*256*128;
  jt.src[8]=(const float*)d_in[21]; jt.dst[8]=WKQV2+2L*256*128;  jt.K[8]=128; jt.N[8]=256;  jt.lstr[8]=3L*256*128;
  jt.src[9]=(const float*)d_in[22]; jt.dst[9]=WO2T;              jt.K[9]=256; jt.N[9]=128;  jt.lstr[9]=256L*128;
  jt.src[10]=(const float*)d_in[26];jt.dst[10]=F12T;             jt.K[10]=128;jt.N[10]=512; jt.lstr[10]=512L*128;
  jt.src[11]=(const float*)d_in[28];jt.dst[11]=F22T;             jt.K[11]=512;jt.N[11]=128; jt.lstr[11]=512L*128;
  k_wtall<<<dim3(256,12,4),dim3(256),0,stream>>>(jt);
  {
    long t1 = 4L*640*128;
    k_projconv<<<dim3((int)((t1+255)/256)),dim3(256),0,stream>>>((const float*)d_in[16], PJ1, 620, 640, 128, t1);
    long t2 = 4L*288*64;
    k_projconv<<<dim3((int)((t2+255)/256)),dim3(256),0,stream>>>((const float*)d_in[30], PJ2, 266, 288, 64, t2);
  }

  StageP T;
  T.ln1w=(const float*)d_in[3];  T.ln1b=(const float*)d_in[4];
  T.wob=(const float*)d_in[9];
  T.ln2w=(const float*)d_in[10]; T.ln2b=(const float*)d_in[11];
  T.f1b=(const float*)d_in[13];  T.f2b=(const float*)d_in[15];
  T.wkqvT=WKQV1; T.woT=WO1T; T.f1T=F11T; T.f2T=F21T; T.projb=PJ1;
  T.n=128; T.D=256; T.H=5; T.dh=128; T.I=640; T.M=620; T.Mp=640;

  StageP Ms;
  Ms.ln1w=(const float*)d_in[17]; Ms.ln1b=(const float*)d_in[18];
  Ms.wob=(const float*)d_in[23];
  Ms.ln2w=(const float*)d_in[24]; Ms.ln2b=(const float*)d_in[25];
  Ms.f1b=(const float*)d_in[27];  Ms.f2b=(const float*)d_in[29];
  Ms.wkqvT=WKQV2; Ms.woT=WO2T; Ms.f1T=F12T; Ms.f2T=F22T; Ms.projb=PJ2;
  Ms.n=256; Ms.D=128; Ms.H=4; Ms.dh=64; Ms.I=256; Ms.M=266; Ms.Mp=288;

  k_embed<<<dim3(8192),dim3(256),0,stream>>>(x, lin_w, lin_b, X);
  run_stage<256,128,640,620,10,4>(T, X, KQVb, DDk, CTXT, ATTNb, FFHb,
            KPSUM, DIAG, REDU, stream);
  k_transpose_pe<<<dim3(8192),dim3(256),0,stream>>>(X, X2);
  run_stage<128,64,288,266,5,2>(Ms, X2, KQVb, DDk, CTXT, ATTNb, FFHb,
            KPSUM, DIAG, REDU, stream);
  k_mean<<<dim3(32),dim3(256),0,stream>>>(X2, (float*)d_out);
}